// Round 11
// baseline (5694.641 us; speedup 1.0000x reference)
//
#include <hip/hip_runtime.h>

#define FHH 38
#define FWW 63
#define NPIX 2394        // 38*63
#define BATCH 8
#define CIN 1024
#define CMID 512
#define NSC 21546        // NPIX*9
#define M_TOT 19152      // BATCH*NPIX
#define K_TOT 9216       // CIN*9
#define PRE_N 2000
#define POST_N 300
#define XS_SPLANE 2451456ll          // 64 c16 * 2394 pix * 16 B
#define XS_CSTRIDE 38304ll           // 2394 * 16

typedef double f64x4 __attribute__((ext_vector_type(4)));
typedef int    i32x4 __attribute__((ext_vector_type(4)));

// exact anchors
__device__ const double ANCX1[9] = {-84.,-176.,-360.,-56.,-120.,-248.,-36.,-80.,-168.};
__device__ const double ANCY1[9] = {-40.,-88.,-184.,-56.,-120.,-248.,-80.,-168.,-344.};
__device__ const double ANCX2[9] = {99.,191.,375.,71.,135.,263.,51.,95.,183.};
__device__ const double ANCY2[9] = {55.,103.,199.,71.,135.,263.,95.,183.,359.};

__device__ __forceinline__ int h1f(int l, int t) { return ((l * 16 + t) * 37) % 61 - 30; }
__device__ __forceinline__ int h2f(int l, int t) { return ((l * 16 + t) * 53) % 59 - 29; }

// ---------------------------------------------------------------------------
// f64 MFMA layout probe (R4-verified; feeds the fallback conv)
// ---------------------------------------------------------------------------
__global__ void mfma_probe_kernel(int* __restrict__ tab) {
    const int l = threadIdx.x;
    __shared__ int aiS[64], bjS[64], kbS[64];
    const f64x4 zero = {0.0, 0.0, 0.0, 0.0};
    int di[4] = {-1, -1, -1, -1}, dj[4] = {-1, -1, -1, -1};
    int ai_l = 0, bj_l = 0, ka_l = 0;
    kbS[l] = 0x7fffffff;
    __syncthreads();
    const double bval = __longlong_as_double((long long)(1023 + l) << 52);
    for (int p = 0; p < 64; ++p) {
        double a = (l == p) ? 1.0 : 0.0;
        f64x4 d = __builtin_amdgcn_mfma_f64_16x16x4f64(a, bval, zero, 0, 0, 0);
        int lmin = 0x7fffffff, kmin = 0x7fffffff;
        bool lit[4]; int qv[4];
#pragma unroll
        for (int r = 0; r < 4; ++r) {
            lit[r] = (d[r] != 0.0);
            qv[r] = ((__double2hiint(d[r]) >> 20) & 0x7ff) - 1023;
            if (lit[r]) { lmin = min(lmin, di[r] < 0 ? p : di[r]); kmin = min(kmin, qv[r]); }
        }
#pragma unroll
        for (int off = 32; off > 0; off >>= 1) {
            lmin = min(lmin, __shfl_xor(lmin, off));
            kmin = min(kmin, __shfl_xor(kmin, off));
        }
#pragma unroll
        for (int r = 0; r < 4; ++r)
            if (lit[r]) { di[r] = lmin; atomicMin(&kbS[qv[r]], kmin); }
        if (l == p) { ai_l = lmin; ka_l = kmin; }
    }
    for (int q = 0; q < 64; ++q) {
        double b = (l == q) ? 1.0 : 0.0;
        f64x4 d = __builtin_amdgcn_mfma_f64_16x16x4f64(1.0, b, zero, 0, 0, 0);
        int lmin = 0x7fffffff;
        bool lit[4];
#pragma unroll
        for (int r = 0; r < 4; ++r) {
            lit[r] = (d[r] != 0.0);
            if (lit[r]) lmin = min(lmin, dj[r] < 0 ? q : dj[r]);
        }
#pragma unroll
        for (int off = 32; off > 0; off >>= 1) lmin = min(lmin, __shfl_xor(lmin, off));
#pragma unroll
        for (int r = 0; r < 4; ++r) if (lit[r]) dj[r] = lmin;
        if (l == q) bj_l = lmin;
    }
    aiS[l] = ai_l; bjS[l] = bj_l;
    __syncthreads();
    int kb_l = kbS[l];
    int a_row_rk = 0, a_k_rk = 0, b_k_rk = 0, b_col_rk = 0;
    for (int t = 0; t < 64; ++t) {
        a_row_rk += (aiS[t] == t && t < ai_l);
        b_col_rk += (bjS[t] == t && t < bj_l);
        a_k_rk   += (kbS[t] == t && t < ka_l);
        b_k_rk   += (kbS[t] == t && t < kb_l);
    }
    tab[l] = a_row_rk; tab[64 + l] = a_k_rk; tab[128 + l] = b_k_rk; tab[192 + l] = b_col_rk;
#pragma unroll
    for (int r = 0; r < 4; ++r) {
        int dr = 0, dc = 0;
        for (int t = 0; t < 64; ++t) {
            dr += (aiS[t] == t && t < di[r]);
            dc += (bjS[t] == t && t < dj[r]);
        }
        tab[256 + l * 4 + r] = dr;
        tab[512 + l * 4 + r] = dc;
    }
}

__global__ void flaginit_kernel(int* __restrict__ f) {
    if (threadIdx.x == 0) { f[0] = 0; f[1] = 0; f[2] = 0; f[3] = 0; f[4] = 0; }
}

// ---------------------------------------------------------------------------
// i8 MFMA probe + self-validation (R9-verified: flags[0] became 1 on HW)
// ---------------------------------------------------------------------------
__global__ void i8_probe_kernel(int* __restrict__ itab, int* __restrict__ flags) {
    const int l = threadIdx.x;
    __shared__ int aiS[64], bjS[64], kbS[64];
    __shared__ int pOf[64], qOf[64];
    const i32x4 zero = {0, 0, 0, 0};
    const i32x4 ones = {0x01010101, 0x01010101, 0x01010101, 0x01010101};
    int di[4] = {-1, -1, -1, -1}, dj[4] = {-1, -1, -1, -1};
    int ai_l = -1, bj_l = -1, ka_l = -1;
    kbS[l] = 0x7fffffff; pOf[l] = 0; qOf[l] = 0;
    __syncthreads();

    for (int p = 0; p < 64; ++p) {
        i32x4 a = (l == p) ? ones : zero;
        i32x4 d = __builtin_amdgcn_mfma_i32_16x16x64_i8(a, ones, zero, 0, 0, 0);
        int lmin = 0x7fffffff;
        bool lit[4];
#pragma unroll
        for (int r = 0; r < 4; ++r) {
            lit[r] = (d[r] != 0);
            if (lit[r]) lmin = min(lmin, di[r] < 0 ? p : di[r]);
        }
#pragma unroll
        for (int off = 32; off > 0; off >>= 1) lmin = min(lmin, __shfl_xor(lmin, off));
#pragma unroll
        for (int r = 0; r < 4; ++r) if (lit[r]) di[r] = lmin;
        if (l == p) ai_l = lmin;
    }
    for (int q = 0; q < 64; ++q) {
        i32x4 b = (l == q) ? ones : zero;
        i32x4 d = __builtin_amdgcn_mfma_i32_16x16x64_i8(ones, b, zero, 0, 0, 0);
        int lmin = 0x7fffffff;
        bool lit[4];
#pragma unroll
        for (int r = 0; r < 4; ++r) {
            lit[r] = (d[r] != 0);
            if (lit[r]) lmin = min(lmin, dj[r] < 0 ? q : dj[r]);
        }
#pragma unroll
        for (int off = 32; off > 0; off >>= 1) lmin = min(lmin, __shfl_xor(lmin, off));
#pragma unroll
        for (int r = 0; r < 4; ++r) if (lit[r]) dj[r] = lmin;
        if (l == q) bj_l = lmin;
    }
    {
        unsigned bw = (unsigned)(l + 1);
        bw |= bw << 8; bw |= bw << 16;
        i32x4 bq = {(int)bw, (int)bw, (int)bw, (int)bw};
        for (int p = 0; p < 64; ++p) {
            i32x4 a = (l == p) ? ones : zero;
            i32x4 d = __builtin_amdgcn_mfma_i32_16x16x64_i8(a, bq, zero, 0, 0, 0);
            int kmin = 0x7fffffff;
            bool lit[4]; int qv[4];
#pragma unroll
            for (int r = 0; r < 4; ++r) {
                lit[r] = (d[r] != 0);
                qv[r] = d[r] / 16 - 1;
                if (lit[r]) kmin = min(kmin, qv[r]);
            }
#pragma unroll
            for (int off = 32; off > 0; off >>= 1) kmin = min(kmin, __shfl_xor(kmin, off));
#pragma unroll
            for (int r = 0; r < 4; ++r)
                if (lit[r] && qv[r] >= 0 && qv[r] < 64) atomicMin(&kbS[qv[r]], kmin);
            if (l == p) ka_l = kmin;
        }
    }
    aiS[l] = ai_l; bjS[l] = bj_l;
    __syncthreads();
    int kb_l = kbS[l];
    int rA = 0, gA = 0, gB = 0, cB = 0;
    for (int t = 0; t < 64; ++t) {
        rA += (aiS[t] == t && t < ai_l);
        cB += (bjS[t] == t && t < bj_l);
        gA += (kbS[t] == t && t < ka_l);
        gB += (kbS[t] == t && t < kb_l);
    }
    itab[l] = rA; itab[64 + l] = gA; itab[128 + l] = gB; itab[192 + l] = cB;
    int dR[4], dC[4];
#pragma unroll
    for (int r = 0; r < 4; ++r) {
        int dr = 0, dc = 0;
        for (int t = 0; t < 64; ++t) {
            dr += (aiS[t] == t && t < di[r]);
            dc += (bjS[t] == t && t < dj[r]);
        }
        dR[r] = dr; dC[r] = dc;
        itab[256 + l * 4 + r] = dr;
        itab[512 + l * 4 + r] = dc;
    }
    __syncthreads();
    bool ok = (rA < 16) && (gA < 4) && (cB < 16) && (gB < 4);
    if (ok) { pOf[rA * 4 + gA] = l; qOf[cB * 4 + gB] = l; }
    __syncthreads();
    unsigned wa[4], wb[4];
#pragma unroll
    for (int dw = 0; dw < 4; ++dw) {
        unsigned a = 0, b = 0;
#pragma unroll
        for (int by = 0; by < 4; ++by) {
            int t = dw * 4 + by;
            a |= ((unsigned)(h1f(l, t) & 0xff)) << (8 * by);
            b |= ((unsigned)(h2f(l, t) & 0xff)) << (8 * by);
        }
        wa[dw] = a; wb[dw] = b;
    }
    i32x4 va = {(int)wa[0], (int)wa[1], (int)wa[2], (int)wa[3]};
    i32x4 vb = {(int)wb[0], (int)wb[1], (int)wb[2], (int)wb[3]};
    i32x4 d = __builtin_amdgcn_mfma_i32_16x16x64_i8(va, vb, zero, 0, 0, 0);
#pragma unroll
    for (int r = 0; r < 4; ++r) {
        if (dR[r] >= 16 || dC[r] >= 16) { ok = false; continue; }
        int ref = 0;
        for (int g = 0; g < 4; ++g) {
            int p = pOf[dR[r] * 4 + g], q = qOf[dC[r] * 4 + g];
            for (int t = 0; t < 16; ++t) ref += h1f(p, t) * h2f(q, t);
        }
        ok = ok && (d[r] == ref);
    }
    unsigned long long mb = __ballot(ok);
    if (l == 0) flags[0] = (mb == ~0ull) ? 1 : 0;
}

__global__ void maxabs_kernel(const float* __restrict__ p, long long n, unsigned* __restrict__ out) {
    unsigned mx = 0u;
    for (long long i = blockIdx.x * 256ll + threadIdx.x; i < n; i += (long long)gridDim.x * 256)
        mx = max(mx, __float_as_uint(p[i]) & 0x7fffffffu);
#pragma unroll
    for (int off = 32; off > 0; off >>= 1)
        mx = max(mx, (unsigned)__shfl_xor((int)mx, off));
    if ((threadIdx.x & 63) == 0) atomicMax(out, mx);
}

__global__ void prep_kernel(int* __restrict__ flags) {
    if (threadIdx.x == 0) {
        unsigned ax = (unsigned)flags[3], aw = (unsigned)flags[4];
        flags[1] = (int)((ax >> 23) & 255u) - 127 + 2;   // EA
        flags[2] = (int)((aw >> 23) & 255u) - 127 + 2;   // EB
    }
}

// slice x (ONE batch) -> xs[s][c16][pix][16] i8 digits (R10-proven)
__global__ __launch_bounds__(256) void slice_x_kernel(
    const float* __restrict__ x, const int* __restrict__ flags,
    int batch, signed char* __restrict__ xs) {
    if (flags[0] != 1) return;
    const int EA = flags[1];
    const float sA = __int_as_float((127 - EA) << 23);   // exact 2^-EA
    const int pix = blockIdx.x * 256 + threadIdx.x;
    const int c16 = blockIdx.y;
    if (pix >= NPIX) return;
    unsigned wds[6][4];
#pragma unroll
    for (int s = 0; s < 6; ++s)
#pragma unroll
        for (int dw = 0; dw < 4; ++dw) wds[s][dw] = 0u;
    const float* ap = x + ((size_t)(batch * CIN + c16 * 16)) * NPIX + pix;
#pragma unroll
    for (int t = 0; t < 16; ++t) {
        float u = ap[(size_t)t * NPIX] * sA;
#pragma unroll
        for (int s = 0; s < 6; ++s) {
            u *= 128.f;
            float dd = rintf(u);
            u -= dd;
            wds[s][t >> 2] |= ((unsigned)((int)dd & 0xff)) << ((t & 3) * 8);
        }
    }
#pragma unroll
    for (int s = 0; s < 6; ++s)
        *(i32x4*)(xs + (size_t)s * XS_SPLANE + (size_t)c16 * XS_CSTRIDE + (size_t)pix * 16) =
            (i32x4){(int)wds[s][0], (int)wds[s][1], (int)wds[s][2], (int)wds[s][3]};
}

// slice W_conv -> ws8[s][co][k] i8 (5 digits), k=(kh*3+kw)*1024+ci  (R9-proven)
__global__ void slice_w_kernel(const float* __restrict__ W, const int* __restrict__ flags,
                               signed char* __restrict__ ws8) {
    if (flags[0] != 1) return;
    const int EB = flags[2];
    long long gid = blockIdx.x * 256ll + threadIdx.x;
    if (gid >= (long long)CMID * K_TOT) return;
    int co = (int)(gid / K_TOT);
    int k = (int)(gid - (long long)co * K_TOT);
    int pl = k >> 10, ci = k & 1023;
    double u = ldexp((double)W[((size_t)co * CIN + ci) * 9 + pl], -EB);
#pragma unroll
    for (int s = 0; s < 5; ++s) {
        u *= 128.0; double d = rint(u); u -= d;
        ws8[(size_t)s * (512ll * K_TOT) + (size_t)co * K_TOT + k] = (signed char)(int)d;
    }
}

// ---------------------------------------------------------------------------
// i8-Ozaki conv, ONE batch, LDS-free & barrier-free. Wave tile 16m x 32n
// (acc[6][2]), 4 waves/block stacked in m (64m x 32n per block), grid 608.
// XCD-locality swizzle: xcd = id&7 owns n-tiles {xcd, xcd+8} for ALL m ->
// per-XCD B footprint 2.95 MB (L2-resident). Indexing = rt=0 specialization
// of the R10-proven mapping.
// ---------------------------------------------------------------------------
__global__ __launch_bounds__(256, 3) void conv3x3_i8b(
    const signed char* __restrict__ xs, const signed char* __restrict__ ws8,
    const float* __restrict__ bconv, const int* __restrict__ flags,
    const int* __restrict__ itab, int batch, double* __restrict__ feat) {
    if (flags[0] != 1) return;
    const int EA = flags[1], EB = flags[2];
    const int tid = threadIdx.x;
    const int l = tid & 63, w = tid >> 6;        // wave 0..3
    const int id = blockIdx.x;                   // 0..607
    const int r8 = id & 7;
    const int q = id >> 3;                       // 0..75
    const int qh = q / 38;                       // 0..1
    const int n_blk = r8 + 8 * qh;               // 0..15
    const int m_blk = q - 38 * qh;               // 0..37
    const int n0 = n_blk * 32;
    const int mbase = m_blk * 64 + w * 16;

    const int rA = itab[l];
    const int gA = itab[64 + l];
    const int gB = itab[128 + l];
    const int cB = itab[192 + l];
    int dR[4], dC[4];
#pragma unroll
    for (int r = 0; r < 4; ++r) { dR[r] = itab[256 + l * 4 + r]; dC[r] = itab[512 + l * 4 + r]; }

    const int m = mbase + rA;
    const bool vm = (m < NPIX);
    const int mm = vm ? m : 0;
    const int yy = mm / FWW;
    const int xx = mm - yy * FWW;

    i32x4 acc[6][2];                             // [s][ct]
#pragma unroll
    for (int s = 0; s < 6; ++s)
#pragma unroll
        for (int ct = 0; ct < 2; ++ct) acc[s][ct] = (i32x4){0, 0, 0, 0};

    size_t bofs[5][2];
#pragma unroll
    for (int j = 0; j < 5; ++j)
#pragma unroll
        for (int ct = 0; ct < 2; ++ct)
            bofs[j][ct] = ((size_t)(j * 512 + n0 + ct * 16 + cB)) * K_TOT + (size_t)gB * 16;

#pragma unroll 2
    for (int kc = 0; kc < 144; ++kc) {
        const int pl = kc >> 4;
        const int kh = pl / 3, kw = pl - kh * 3;
        const size_t cbase = (size_t)(((kc & 15) << 2) + gA) * XS_CSTRIDE;
        const int iy = yy + kh - 1, ix = xx + kw - 1;
        const bool ok = vm && iy >= 0 && iy < FHH && ix >= 0 && ix < FWW;
        const int pix = ok ? (iy * FWW + ix) : 0;
        const signed char* ap = xs + cbase + (size_t)pix * 16;
        i32x4 af[6];
#pragma unroll
        for (int s = 0; s < 6; ++s) {
            i32x4 v = *(const i32x4*)(ap + (size_t)s * XS_SPLANE);
            if (!ok) v = (i32x4){0, 0, 0, 0};
            af[s] = v;
        }
        const size_t kofs = (size_t)pl * 1024 + (size_t)((kc & 15) << 6);
#pragma unroll
        for (int j = 0; j < 5; ++j) {
            i32x4 bf0 = *(const i32x4*)(ws8 + bofs[j][0] + kofs);
            i32x4 bf1 = *(const i32x4*)(ws8 + bofs[j][1] + kofs);
#pragma unroll
            for (int i = 0; i + j <= 5; ++i) {
                acc[i + j][0] = __builtin_amdgcn_mfma_i32_16x16x64_i8(af[i], bf0, acc[i + j][0], 0, 0, 0);
                acc[i + j][1] = __builtin_amdgcn_mfma_i32_16x16x64_i8(af[i], bf1, acc[i + j][1], 0, 0, 0);
            }
        }
    }
    double sc[6];
#pragma unroll
    for (int s = 0; s < 6; ++s) sc[s] = ldexp(1.0, EA + EB - 7 * (s + 2));
#pragma unroll
    for (int ct = 0; ct < 2; ++ct)
#pragma unroll
        for (int r = 0; r < 4; ++r) {
            int grow = mbase + dR[r];
            int gcol = n0 + ct * 16 + dC[r];
            if (grow < NPIX) {
                double v = (double)bconv[gcol];
#pragma unroll
                for (int s = 0; s < 6; ++s) v += sc[s] * (double)acc[s][ct][r];
                feat[((size_t)(batch * NPIX + grow)) * CMID + gcol] = fmax(v, 0.0);
            }
        }
}

// K0: W_conv -> Wt[k][co] fp32 (fallback)
__global__ void wt3x3_kernel(const float* __restrict__ W, float* __restrict__ Wt) {
    int gid = blockIdx.x * 256 + threadIdx.x;
    if (gid >= K_TOT * CMID) return;
    int co = gid & 511;
    int k  = gid >> 9;
    int pl = k >> 10;
    int ci = k & 1023;
    Wt[gid] = W[((size_t)co * CIN + ci) * 9 + pl];
}

__global__ void wt1x1_kernel(const float* __restrict__ Wc, const float* __restrict__ Wb,
                             double* __restrict__ Wt2pD) {
    int gid = blockIdx.x * 256 + threadIdx.x;
    if (gid >= CMID * 64) return;
    int n = gid & 63, k = gid >> 6;
    double v = 0.0;
    if (n < 18)      v = (double)Wc[(size_t)n * CMID + k];
    else if (n < 54) v = (double)Wb[(size_t)(n - 18) * CMID + k];
    Wt2pD[gid] = v;
}

// Fallback f64 MFMA conv (R6-verified), runs only when flags[0]==0
#define ASZ (32 * 72)
__global__ __launch_bounds__(256, 4) void conv3x3_mfma(
    const float* __restrict__ x, const float* __restrict__ Wt,
    const float* __restrict__ bconv, const int* __restrict__ tab,
    const int* __restrict__ flags, double* __restrict__ feat) {
    if (flags[0] == 1) return;
    __shared__ float As[2 * ASZ];
    __shared__ float Bs[2 * ASZ];
    const int tid = threadIdx.x;
    const int lane = tid & 63;
    const int wave = tid >> 6;
    const int wm = wave >> 1;
    const int wn = wave & 1;
    const int n0 = blockIdx.x * 64;
    const int m0 = blockIdx.y * 64;

    const int aRow = tab[lane];
    const int aK   = tab[64 + lane];
    const int bK   = tab[128 + lane];
    const int bCol = tab[192 + lane];
    int dRow[4], dCol[4];
#pragma unroll
    for (int r = 0; r < 4; ++r) {
        dRow[r] = tab[256 + lane * 4 + r];
        dCol[r] = tab[512 + lane * 4 + r];
    }
    const int mm = tid & 63;
    const int t6 = tid >> 6;
    const int m = m0 + mm;
    const bool vm = (m < M_TOT);
    int b = 0, yy = 0, xx = 0;
    if (vm) { b = m / NPIX; int r = m - b * NPIX; yy = r / FWW; xx = r - yy * FWW; }
    const int bk2 = tid >> 4;
    const int bn2 = (tid & 15) << 2;

    f64x4 acc[2][2];
#pragma unroll
    for (int i = 0; i < 2; ++i)
#pragma unroll
        for (int j = 0; j < 2; ++j) acc[i][j] = (f64x4){0.0, 0.0, 0.0, 0.0};

    const float* aBase = &As[aK * 72 + wm * 32 + aRow];
    const float* bBase = &Bs[bK * 72 + wn * 32 + bCol];

#define STAGE_REGS(KC, VA, VB0, VB1) do {                                     \
        const int pl_ = (KC) >> 5;                                            \
        const int kh_ = pl_ / 3, kw_ = pl_ - kh_ * 3;                         \
        const int ci0_ = ((KC) & 31) << 5;                                    \
        const int iy_ = yy + kh_ - 1, ix_ = xx + kw_ - 1;                     \
        const bool ok_ = vm && (iy_ >= 0) && (iy_ < FHH) && (ix_ >= 0) && (ix_ < FWW); \
        const float* ap_ = x + ((size_t)(b * CIN + ci0_ + t6)) * NPIX + iy_ * FWW + ix_; \
        _Pragma("unroll")                                                     \
        for (int r = 0; r < 8; ++r) {                                         \
            float v_ = 0.f;                                                   \
            if (ok_) v_ = ap_[(size_t)r * 4 * NPIX];                          \
            VA[r] = v_;                                                       \
        }                                                                     \
        const float4* wp_ = (const float4*)(Wt + (size_t)(((KC) << 5) + bk2) * CMID + n0 + bn2); \
        VB0 = wp_[0];                                                         \
        VB1 = wp_[2048];                                                      \
    } while (0)

#define WRITE_TILE(BUF, VA, VB0, VB1) do {                                    \
        _Pragma("unroll")                                                     \
        for (int r = 0; r < 8; ++r)                                           \
            As[(BUF) * ASZ + (t6 + r * 4) * 72 + mm] = VA[r];                 \
        *(float4*)&Bs[(BUF) * ASZ + bk2 * 72 + bn2] = VB0;                    \
        *(float4*)&Bs[(BUF) * ASZ + (bk2 + 16) * 72 + bn2] = VB1;             \
    } while (0)

#define MFMA_PHASE(BUF) do {                                                  \
        _Pragma("unroll")                                                     \
        for (int ks = 0; ks < 8; ++ks) {                                      \
            double a0 = (double)aBase[(BUF) * ASZ + ks * 288];                \
            double a1 = (double)aBase[(BUF) * ASZ + ks * 288 + 16];           \
            double b0 = (double)bBase[(BUF) * ASZ + ks * 288];                \
            double b1 = (double)bBase[(BUF) * ASZ + ks * 288 + 16];           \
            acc[0][0] = __builtin_amdgcn_mfma_f64_16x16x4f64(a0, b0, acc[0][0], 0, 0, 0); \
            acc[0][1] = __builtin_amdgcn_mfma_f64_16x16x4f64(a0, b1, acc[0][1], 0, 0, 0); \
            acc[1][0] = __builtin_amdgcn_mfma_f64_16x16x4f64(a1, b0, acc[1][0], 0, 0, 0); \
            acc[1][1] = __builtin_amdgcn_mfma_f64_16x16x4f64(a1, b1, acc[1][1], 0, 0, 0); \
        }                                                                     \
    } while (0)

    float va[8]; float4 vb0, vb1;
    float wa[8]; float4 wb0, wb1;
    STAGE_REGS(0, va, vb0, vb1);
    WRITE_TILE(0, va, vb0, vb1);
    __syncthreads();
    for (int kc = 0; kc < 288; kc += 2) {
        STAGE_REGS(kc + 1, wa, wb0, wb1);
        MFMA_PHASE(0);
        WRITE_TILE(1, wa, wb0, wb1);
        __syncthreads();
        if (kc + 2 < 288) {
            STAGE_REGS(kc + 2, va, vb0, vb1);
            MFMA_PHASE(1);
            WRITE_TILE(0, va, vb0, vb1);
            __syncthreads();
        } else {
            MFMA_PHASE(1);
        }
    }
#undef STAGE_REGS
#undef WRITE_TILE
#undef MFMA_PHASE
#pragma unroll
    for (int mi = 0; mi < 2; ++mi)
#pragma unroll
        for (int nj = 0; nj < 2; ++nj)
#pragma unroll
            for (int r = 0; r < 4; ++r) {
                int mg  = m0 + wm * 32 + mi * 16 + dRow[r];
                int col = n0 + wn * 32 + nj * 16 + dCol[r];
                if (mg < M_TOT)
                    feat[(size_t)mg * CMID + col] =
                        fmax(acc[mi][nj][r] + (double)bconv[col], 0.0);
            }
}

// K2: 1x1 convs, fp64
__global__ __launch_bounds__(256) void conv1x1_kernel(
    const double* __restrict__ feat, const double* __restrict__ Wt2pD,
    const float* __restrict__ bcls, const float* __restrict__ bbx,
    double* __restrict__ out54) {
    __shared__ double As[4 * 512];
    __shared__ double Bsh[64 * 64];
    int tid = threadIdx.x;
    int m0 = blockIdx.x * 4;
    for (int off = tid; off < 2048; off += 256) As[off] = feat[(size_t)m0 * CMID + off];
    int p = tid >> 6, n = tid & 63;
    double acc = 0.0;
    for (int c = 0; c < 8; ++c) {
        __syncthreads();
        for (int off = tid; off < 4096; off += 256) Bsh[off] = Wt2pD[c * 4096 + off];
        __syncthreads();
        const double* ap = &As[p * 512 + c * 64];
#pragma unroll 8
        for (int k2 = 0; k2 < 64; ++k2) acc = fma(ap[k2], Bsh[k2 * 64 + n], acc);
    }
    if (n < 54) {
        double bias = (double)((n < 18) ? bcls[n] : bbx[n - 18]);
        out54[(size_t)(m0 + p) * 64 + n] = acc + bias;
    }
}

// K2b: softmax-pair + bbox decode + clip, fp64
__global__ void proposals_kernel(const double* __restrict__ out54, const float* __restrict__ iminfo,
                                 double* __restrict__ scoresD, double* __restrict__ propsD) {
    int gid = blockIdx.x * 256 + threadIdx.x;
    if (gid >= BATCH * NSC) return;
    int b = gid / NSC;
    int rem = gid - b * NSC;
    int p = rem / 9;
    int a = rem - p * 9;
    int y = p / FWW, x = p - y * FWW;
    int m = b * NPIX + p;
    const double* row = out54 + (size_t)m * 64;
    double s0 = row[a], s1 = row[9 + a];
    double mx = fmax(s0, s1);
    double e0 = exp(s0 - mx), e1 = exp(s1 - mx);
    scoresD[gid] = e1 / (e0 + e1);
    double dx = row[18 + 4 * a], dy = row[19 + 4 * a], dw = row[20 + 4 * a], dh = row[21 + 4 * a];
    double ax1 = x * 16.0 + ANCX1[a], ay1 = y * 16.0 + ANCY1[a];
    double ax2 = x * 16.0 + ANCX2[a], ay2 = y * 16.0 + ANCY2[a];
    double w = ax2 - ax1 + 1.0, h = ay2 - ay1 + 1.0;
    double cx = ax1 + 0.5 * w, cy = ay1 + 0.5 * h;
    double px = dx * w + cx, py = dy * h + cy;
    double pw = exp(dw) * w, ph = exp(dh) * h;
    double imh = (double)iminfo[b * 3 + 0], imw = (double)iminfo[b * 3 + 1];
    double x1 = fmin(fmax(px - 0.5 * pw, 0.0), imw - 1.0);
    double y1 = fmin(fmax(py - 0.5 * ph, 0.0), imh - 1.0);
    double x2 = fmin(fmax(px + 0.5 * pw, 0.0), imw - 1.0);
    double y2 = fmin(fmax(py + 0.5 * ph, 0.0), imh - 1.0);
    double* o = propsD + (size_t)gid * 4;
    o[0] = x1; o[1] = y1; o[2] = x2; o[3] = y2;
}

// K3: exact top-2000 radix-select + bitonic
__global__ __launch_bounds__(256) void select_kernel(const double* __restrict__ scoresD,
                                                     const double* __restrict__ propsD,
                                                     double* __restrict__ boxesD) {
    __shared__ unsigned int hist4[4][256];
    __shared__ unsigned int histf[256];
    __shared__ unsigned long long keys[2048];
    __shared__ unsigned long long sh_thr;
    __shared__ int sh_need;
    __shared__ int cnt;
    const int b = blockIdx.x, tid = threadIdx.x;
    const int w4 = tid >> 6;
    const double* sc = scoresD + (size_t)b * NSC;

    unsigned long long prefix = 0ull;
    int need = PRE_N;
    for (int d = 7; d >= 0; --d) {
        for (int z = tid; z < 1024; z += 256) ((unsigned int*)hist4)[z] = 0u;
        __syncthreads();
        const int shift = d * 8;
        const unsigned long long maskAbove = (d == 7) ? 0ull : (~0ull << (shift + 8));
        for (int i = tid; i < NSC; i += 256) {
            unsigned long long sb = (unsigned long long)__double_as_longlong(sc[i]);
            unsigned long long key = (sb & ~0x7FFFull) | (unsigned long long)((~i) & 0x7FFF);
            if (((key ^ prefix) & maskAbove) == 0ull)
                atomicAdd(&hist4[w4][(unsigned int)(key >> shift) & 255u], 1u);
        }
        __syncthreads();
        histf[tid] = hist4[0][tid] + hist4[1][tid] + hist4[2][tid] + hist4[3][tid];
        __syncthreads();
        if (tid == 0) {
            int acc = 0, v = 255;
            for (; v > 0; --v) {
                int c = (int)histf[v];
                if (acc + c >= need) break;
                acc += c;
            }
            sh_thr = prefix | ((unsigned long long)(unsigned int)v << shift);
            sh_need = need - acc;
        }
        __syncthreads();
        prefix = sh_thr;
        need = sh_need;
        __syncthreads();
    }
    if (tid == 0) cnt = 0;
    __syncthreads();
    for (int i = tid; i < NSC; i += 256) {
        unsigned long long sb = (unsigned long long)__double_as_longlong(sc[i]);
        unsigned long long key = (sb & ~0x7FFFull) | (unsigned long long)((~i) & 0x7FFF);
        if (key >= prefix) {
            int slot = atomicAdd(&cnt, 1);
            if (slot < 2048) keys[slot] = key;
        }
    }
    __syncthreads();
    int c0 = cnt;
    for (int i = tid; i < 2048; i += 256)
        if (i >= c0) keys[i] = 0ull;
    for (int k2 = 2; k2 <= 2048; k2 <<= 1)
        for (int j = k2 >> 1; j > 0; j >>= 1) {
            __syncthreads();
            for (int i = tid; i < 2048; i += 256) {
                int l = i ^ j;
                if (l > i) {
                    unsigned long long a = keys[i], c = keys[l];
                    bool up = (i & k2) == 0;
                    if (up ? (a < c) : (a > c)) { keys[i] = c; keys[l] = a; }
                }
            }
        }
    __syncthreads();
    const double* pr = propsD + (size_t)b * NSC * 4;
    double* bs = boxesD + (size_t)b * PRE_N * 4;
    for (int r = tid; r < PRE_N; r += 256) {
        int idx = (int)((~keys[r]) & 0x7FFF);
        if (idx >= NSC) idx = 0;
        bs[r * 4 + 0] = pr[(size_t)idx * 4 + 0];
        bs[r * 4 + 1] = pr[(size_t)idx * 4 + 1];
        bs[r * 4 + 2] = pr[(size_t)idx * 4 + 2];
        bs[r * 4 + 3] = pr[(size_t)idx * 4 + 3];
    }
}

// K4a: fp64 IoU suppression bitmask
__global__ __launch_bounds__(256) void iou_mask_kernel(const double* __restrict__ boxesD,
                                                       unsigned long long* __restrict__ supmask) {
    __shared__ double bx[PRE_N * 4];
    int b = blockIdx.x;
    int i0 = blockIdx.y * 80;
    const double* src = boxesD + (size_t)b * PRE_N * 4;
    for (int o = threadIdx.x; o < PRE_N * 4; o += 256) bx[o] = src[o];
    __syncthreads();
    int ty = threadIdx.x >> 5, jw = threadIdx.x & 31;
    for (int ii = ty; ii < 80; ii += 8) {
        int i = i0 + ii;
        double bix1 = bx[i * 4 + 0], biy1 = bx[i * 4 + 1], bix2 = bx[i * 4 + 2], biy2 = bx[i * 4 + 3];
        double areai = (bix2 - bix1 + 1.0) * (biy2 - biy1 + 1.0);
        unsigned long long bits = 0ull;
        for (int t = 0; t < 64; ++t) {
            int j = t * 32 + jw;
            if (j > i && j < PRE_N) {
                double bjx1 = bx[j * 4 + 0], bjy1 = bx[j * 4 + 1], bjx2 = bx[j * 4 + 2], bjy2 = bx[j * 4 + 3];
                double iw = fmin(bix2, bjx2) - fmax(bix1, bjx1) + 1.0; iw = fmax(iw, 0.0);
                double ih = fmin(biy2, bjy2) - fmax(biy1, bjy1) + 1.0; ih = fmax(ih, 0.0);
                double inter = iw * ih;
                double areaj = (bjx2 - bjx1 + 1.0) * (bjy2 - bjy1 + 1.0);
                double iou = inter / (areai + areaj - inter);
                if (iou > 0.7) bits |= (1ull << t);
            }
        }
        supmask[((size_t)b * PRE_N + i) * 32 + jw] = bits;
    }
}

// K4b: greedy suppression + first-300 + fp32 output
__global__ void nms_final_kernel(const unsigned long long* __restrict__ supmask,
                                 const double* __restrict__ boxesD,
                                 float* __restrict__ out) {
    int b = blockIdx.x;
    int lane = threadIdx.x;
    int w = lane & 31;
    const unsigned long long* mask = supmask + (size_t)b * PRE_N * 32;
    int nbits = (w < 16) ? 63 : 62;
    unsigned long long kw = (1ull << nbits) - 1ull;
    unsigned long long rr[16];
#pragma unroll
    for (int d2 = 0; d2 < 16; ++d2) rr[d2] = mask[d2 * 32 + w];
    for (int i = 0; i < PRE_N; i += 16) {
#pragma unroll
        for (int u2 = 0; u2 < 16; ++u2) {
            int ii = i + u2;
            unsigned long long rcur = rr[u2];
            int ip = ii + 16;
            rr[u2] = (ip < PRE_N) ? mask[ip * 32 + w] : 0ull;
            unsigned long long kword = __shfl(kw, ii & 31);
            if ((kword >> (ii >> 5)) & 1ull) kw &= ~rcur;
        }
    }
    __shared__ unsigned long long keepw[32];
    __shared__ int pos[POST_N];
    if (lane < 32) keepw[lane] = kw;
    __syncthreads();
    if (lane == 0) {
        int c2 = 0;
        for (int j = 0; j < PRE_N && c2 < POST_N; ++j)
            if ((keepw[j & 31] >> (j >> 5)) & 1ull) pos[c2++] = j;
        for (int j = 0; j < PRE_N && c2 < POST_N; ++j)
            if (!((keepw[j & 31] >> (j >> 5)) & 1ull)) pos[c2++] = j;
    }
    __syncthreads();
    for (int r = lane; r < POST_N; r += 64) {
        int p = pos[r];
        const double* bxp = boxesD + ((size_t)b * PRE_N + p) * 4;
        float* o = out + ((size_t)b * POST_N + r) * 5;
        o[0] = (float)b; o[1] = (float)bxp[0]; o[2] = (float)bxp[1];
        o[3] = (float)bxp[2]; o[4] = (float)bxp[3];
    }
    if (b == 0 && lane == 0) { out[BATCH * POST_N * 5] = 0.f; out[BATCH * POST_N * 5 + 1] = 0.f; }
}

extern "C" void kernel_launch(void* const* d_in, const int* in_sizes, int n_in,
                              void* d_out, int out_size, void* d_ws, size_t ws_size,
                              hipStream_t stream) {
    (void)in_sizes; (void)n_in; (void)out_size;
    const float* base_feat = (const float*)d_in[0];
    const float* im_info   = (const float*)d_in[1];
    const float* W_conv    = (const float*)d_in[4];
    const float* b_conv    = (const float*)d_in[5];
    const float* W_cls     = (const float*)d_in[6];
    const float* b_cls     = (const float*)d_in[7];
    const float* W_bbox    = (const float*)d_in[8];
    const float* b_bbox    = (const float*)d_in[9];
    float* out = (float*)d_out;

    // Layout (total 118,740,096 B <= R9/R10-proven ws bound):
    char* W = (char*)d_ws;
    double* featD   = (double*)W;                        // [0 .. 78,446,592)
    double* out54D  = (double*)(W + 78446592);           // +9,805,824
    double* scoresD = (double*)(W + 88252416);           // +1,378,944
    double* propsD  = (double*)(W + 89631360);           // +5,515,776 -> 95,147,136
    float*  Wt      = (float*)(W + 95147136);            // +18,874,368 (fallback)
    signed char* ws8 = (signed char*)(W + 95147136);     // +23,592,960 (union w/ Wt)
    // aliases, disjoint lifetimes (audited, unchanged from R10):
    signed char* xs = (signed char*)(W + 78446592);      // 14,708,736 B; dead before conv1x1
    double* Wt2pD   = (double*)(W + 94622848);           // props-tail; dead before proposals writes
    int*    tab     = (int*)(W + 94884992);              // props-tail
    int*    itab    = (int*)(W + 94888064);              // props-tail
    int*    iflags  = (int*)(W + 94891136);              // props-tail
    unsigned long long* supmask = (unsigned long long*)W; // featD dead after conv1x1
    double* boxesD  = scoresD;                           // written at end of select

    bool i8cap = (ws_size >= 118740096ull);

    flaginit_kernel<<<1, 64, 0, stream>>>(iflags);
    mfma_probe_kernel<<<1, 64, 0, stream>>>(tab);
    if (i8cap) {
        i8_probe_kernel<<<1, 64, 0, stream>>>(itab, iflags);
        maxabs_kernel<<<1024, 256, 0, stream>>>(base_feat, (long long)BATCH * CIN * NPIX,
                                                (unsigned*)&iflags[3]);
        maxabs_kernel<<<128, 256, 0, stream>>>(W_conv, (long long)CMID * CIN * 9,
                                               (unsigned*)&iflags[4]);
        prep_kernel<<<1, 64, 0, stream>>>(iflags);
    }
    wt3x3_kernel<<<(K_TOT * CMID + 255) / 256, 256, 0, stream>>>(W_conv, Wt);
    wt1x1_kernel<<<(CMID * 64 + 255) / 256, 256, 0, stream>>>(W_cls, W_bbox, Wt2pD);
    if (i8cap) {
        slice_w_kernel<<<(int)((4718592 + 255) / 256), 256, 0, stream>>>(W_conv, iflags, ws8);
        for (int b = 0; b < BATCH; ++b) {
            slice_x_kernel<<<dim3(10, 64), 256, 0, stream>>>(base_feat, iflags, b, xs);
            conv3x3_i8b<<<608, 256, 0, stream>>>(xs, ws8, b_conv, iflags, itab, b, featD);
        }
    }
    conv3x3_mfma<<<dim3(8, 300), 256, 0, stream>>>(base_feat, Wt, b_conv, tab, iflags, featD);
    conv1x1_kernel<<<M_TOT / 4, 256, 0, stream>>>(featD, Wt2pD, b_cls, b_bbox, out54D);
    proposals_kernel<<<(BATCH * NSC + 255) / 256, 256, 0, stream>>>(out54D, im_info, scoresD, propsD);
    select_kernel<<<BATCH, 256, 0, stream>>>(scoresD, propsD, boxesD);
    iou_mask_kernel<<<dim3(BATCH, 25), 256, 0, stream>>>(boxesD, supmask);
    nms_final_kernel<<<BATCH, 64, 0, stream>>>(supmask, boxesD, out);
}

// Round 12
// 3685.718 us; speedup vs baseline: 1.5451x; 1.5451x over previous
//
#include <hip/hip_runtime.h>

#define FHH 38
#define FWW 63
#define NPIX 2394        // 38*63
#define BATCH 8
#define CIN 1024
#define CMID 512
#define NSC 21546        // NPIX*9
#define M_TOT 19152      // BATCH*NPIX
#define K_TOT 9216       // CIN*9
#define PRE_N 2000
#define POST_N 300
#define XS_BATCH 14708736ll      // 64 c16 * 2394 pix * 96 B

typedef double f64x4 __attribute__((ext_vector_type(4)));
typedef int    i32x4 __attribute__((ext_vector_type(4)));

// exact anchors
__device__ const double ANCX1[9] = {-84.,-176.,-360.,-56.,-120.,-248.,-36.,-80.,-168.};
__device__ const double ANCY1[9] = {-40.,-88.,-184.,-56.,-120.,-248.,-80.,-168.,-344.};
__device__ const double ANCX2[9] = {99.,191.,375.,71.,135.,263.,51.,95.,183.};
__device__ const double ANCY2[9] = {55.,103.,199.,71.,135.,263.,95.,183.,359.};

__device__ __forceinline__ int h1f(int l, int t) { return ((l * 16 + t) * 37) % 61 - 30; }
__device__ __forceinline__ int h2f(int l, int t) { return ((l * 16 + t) * 53) % 59 - 29; }

// ---------------------------------------------------------------------------
// f64 MFMA layout probe (R4-verified; feeds the fallback conv)
// ---------------------------------------------------------------------------
__global__ void mfma_probe_kernel(int* __restrict__ tab) {
    const int l = threadIdx.x;
    __shared__ int aiS[64], bjS[64], kbS[64];
    const f64x4 zero = {0.0, 0.0, 0.0, 0.0};
    int di[4] = {-1, -1, -1, -1}, dj[4] = {-1, -1, -1, -1};
    int ai_l = 0, bj_l = 0, ka_l = 0;
    kbS[l] = 0x7fffffff;
    __syncthreads();
    const double bval = __longlong_as_double((long long)(1023 + l) << 52);
    for (int p = 0; p < 64; ++p) {
        double a = (l == p) ? 1.0 : 0.0;
        f64x4 d = __builtin_amdgcn_mfma_f64_16x16x4f64(a, bval, zero, 0, 0, 0);
        int lmin = 0x7fffffff, kmin = 0x7fffffff;
        bool lit[4]; int qv[4];
#pragma unroll
        for (int r = 0; r < 4; ++r) {
            lit[r] = (d[r] != 0.0);
            qv[r] = ((__double2hiint(d[r]) >> 20) & 0x7ff) - 1023;
            if (lit[r]) { lmin = min(lmin, di[r] < 0 ? p : di[r]); kmin = min(kmin, qv[r]); }
        }
#pragma unroll
        for (int off = 32; off > 0; off >>= 1) {
            lmin = min(lmin, __shfl_xor(lmin, off));
            kmin = min(kmin, __shfl_xor(kmin, off));
        }
#pragma unroll
        for (int r = 0; r < 4; ++r)
            if (lit[r]) { di[r] = lmin; atomicMin(&kbS[qv[r]], kmin); }
        if (l == p) { ai_l = lmin; ka_l = kmin; }
    }
    for (int q = 0; q < 64; ++q) {
        double b = (l == q) ? 1.0 : 0.0;
        f64x4 d = __builtin_amdgcn_mfma_f64_16x16x4f64(1.0, b, zero, 0, 0, 0);
        int lmin = 0x7fffffff;
        bool lit[4];
#pragma unroll
        for (int r = 0; r < 4; ++r) {
            lit[r] = (d[r] != 0.0);
            if (lit[r]) lmin = min(lmin, dj[r] < 0 ? q : dj[r]);
        }
#pragma unroll
        for (int off = 32; off > 0; off >>= 1) lmin = min(lmin, __shfl_xor(lmin, off));
#pragma unroll
        for (int r = 0; r < 4; ++r) if (lit[r]) dj[r] = lmin;
        if (l == q) bj_l = lmin;
    }
    aiS[l] = ai_l; bjS[l] = bj_l;
    __syncthreads();
    int kb_l = kbS[l];
    int a_row_rk = 0, a_k_rk = 0, b_k_rk = 0, b_col_rk = 0;
    for (int t = 0; t < 64; ++t) {
        a_row_rk += (aiS[t] == t && t < ai_l);
        b_col_rk += (bjS[t] == t && t < bj_l);
        a_k_rk   += (kbS[t] == t && t < ka_l);
        b_k_rk   += (kbS[t] == t && t < kb_l);
    }
    tab[l] = a_row_rk; tab[64 + l] = a_k_rk; tab[128 + l] = b_k_rk; tab[192 + l] = b_col_rk;
#pragma unroll
    for (int r = 0; r < 4; ++r) {
        int dr = 0, dc = 0;
        for (int t = 0; t < 64; ++t) {
            dr += (aiS[t] == t && t < di[r]);
            dc += (bjS[t] == t && t < dj[r]);
        }
        tab[256 + l * 4 + r] = dr;
        tab[512 + l * 4 + r] = dc;
    }
}

__global__ void flaginit_kernel(int* __restrict__ f) {
    if (threadIdx.x == 0) { f[0] = 0; f[1] = 0; f[2] = 0; f[3] = 0; f[4] = 0; }
}

// ---------------------------------------------------------------------------
// i8 MFMA probe + self-validation (R9/R10/R11-verified on HW)
// ---------------------------------------------------------------------------
__global__ void i8_probe_kernel(int* __restrict__ itab, int* __restrict__ flags) {
    const int l = threadIdx.x;
    __shared__ int aiS[64], bjS[64], kbS[64];
    __shared__ int pOf[64], qOf[64];
    const i32x4 zero = {0, 0, 0, 0};
    const i32x4 ones = {0x01010101, 0x01010101, 0x01010101, 0x01010101};
    int di[4] = {-1, -1, -1, -1}, dj[4] = {-1, -1, -1, -1};
    int ai_l = -1, bj_l = -1, ka_l = -1;
    kbS[l] = 0x7fffffff; pOf[l] = 0; qOf[l] = 0;
    __syncthreads();

    for (int p = 0; p < 64; ++p) {
        i32x4 a = (l == p) ? ones : zero;
        i32x4 d = __builtin_amdgcn_mfma_i32_16x16x64_i8(a, ones, zero, 0, 0, 0);
        int lmin = 0x7fffffff;
        bool lit[4];
#pragma unroll
        for (int r = 0; r < 4; ++r) {
            lit[r] = (d[r] != 0);
            if (lit[r]) lmin = min(lmin, di[r] < 0 ? p : di[r]);
        }
#pragma unroll
        for (int off = 32; off > 0; off >>= 1) lmin = min(lmin, __shfl_xor(lmin, off));
#pragma unroll
        for (int r = 0; r < 4; ++r) if (lit[r]) di[r] = lmin;
        if (l == p) ai_l = lmin;
    }
    for (int q = 0; q < 64; ++q) {
        i32x4 b = (l == q) ? ones : zero;
        i32x4 d = __builtin_amdgcn_mfma_i32_16x16x64_i8(ones, b, zero, 0, 0, 0);
        int lmin = 0x7fffffff;
        bool lit[4];
#pragma unroll
        for (int r = 0; r < 4; ++r) {
            lit[r] = (d[r] != 0);
            if (lit[r]) lmin = min(lmin, dj[r] < 0 ? q : dj[r]);
        }
#pragma unroll
        for (int off = 32; off > 0; off >>= 1) lmin = min(lmin, __shfl_xor(lmin, off));
#pragma unroll
        for (int r = 0; r < 4; ++r) if (lit[r]) dj[r] = lmin;
        if (l == q) bj_l = lmin;
    }
    {
        unsigned bw = (unsigned)(l + 1);
        bw |= bw << 8; bw |= bw << 16;
        i32x4 bq = {(int)bw, (int)bw, (int)bw, (int)bw};
        for (int p = 0; p < 64; ++p) {
            i32x4 a = (l == p) ? ones : zero;
            i32x4 d = __builtin_amdgcn_mfma_i32_16x16x64_i8(a, bq, zero, 0, 0, 0);
            int kmin = 0x7fffffff;
            bool lit[4]; int qv[4];
#pragma unroll
            for (int r = 0; r < 4; ++r) {
                lit[r] = (d[r] != 0);
                qv[r] = d[r] / 16 - 1;
                if (lit[r]) kmin = min(kmin, qv[r]);
            }
#pragma unroll
            for (int off = 32; off > 0; off >>= 1) kmin = min(kmin, __shfl_xor(kmin, off));
#pragma unroll
            for (int r = 0; r < 4; ++r)
                if (lit[r] && qv[r] >= 0 && qv[r] < 64) atomicMin(&kbS[qv[r]], kmin);
            if (l == p) ka_l = kmin;
        }
    }
    aiS[l] = ai_l; bjS[l] = bj_l;
    __syncthreads();
    int kb_l = kbS[l];
    int rA = 0, gA = 0, gB = 0, cB = 0;
    for (int t = 0; t < 64; ++t) {
        rA += (aiS[t] == t && t < ai_l);
        cB += (bjS[t] == t && t < bj_l);
        gA += (kbS[t] == t && t < ka_l);
        gB += (kbS[t] == t && t < kb_l);
    }
    itab[l] = rA; itab[64 + l] = gA; itab[128 + l] = gB; itab[192 + l] = cB;
    int dR[4], dC[4];
#pragma unroll
    for (int r = 0; r < 4; ++r) {
        int dr = 0, dc = 0;
        for (int t = 0; t < 64; ++t) {
            dr += (aiS[t] == t && t < di[r]);
            dc += (bjS[t] == t && t < dj[r]);
        }
        dR[r] = dr; dC[r] = dc;
        itab[256 + l * 4 + r] = dr;
        itab[512 + l * 4 + r] = dc;
    }
    __syncthreads();
    bool ok = (rA < 16) && (gA < 4) && (cB < 16) && (gB < 4);
    if (ok) { pOf[rA * 4 + gA] = l; qOf[cB * 4 + gB] = l; }
    __syncthreads();
    unsigned wa[4], wb[4];
#pragma unroll
    for (int dw = 0; dw < 4; ++dw) {
        unsigned a = 0, b = 0;
#pragma unroll
        for (int by = 0; by < 4; ++by) {
            int t = dw * 4 + by;
            a |= ((unsigned)(h1f(l, t) & 0xff)) << (8 * by);
            b |= ((unsigned)(h2f(l, t) & 0xff)) << (8 * by);
        }
        wa[dw] = a; wb[dw] = b;
    }
    i32x4 va = {(int)wa[0], (int)wa[1], (int)wa[2], (int)wa[3]};
    i32x4 vb = {(int)wb[0], (int)wb[1], (int)wb[2], (int)wb[3]};
    i32x4 d = __builtin_amdgcn_mfma_i32_16x16x64_i8(va, vb, zero, 0, 0, 0);
#pragma unroll
    for (int r = 0; r < 4; ++r) {
        if (dR[r] >= 16 || dC[r] >= 16) { ok = false; continue; }
        int ref = 0;
        for (int g = 0; g < 4; ++g) {
            int p = pOf[dR[r] * 4 + g], q = qOf[dC[r] * 4 + g];
            for (int t = 0; t < 16; ++t) ref += h1f(p, t) * h2f(q, t);
        }
        ok = ok && (d[r] == ref);
    }
    unsigned long long mb = __ballot(ok);
    if (l == 0) flags[0] = (mb == ~0ull) ? 1 : 0;
}

__global__ void maxabs_kernel(const float* __restrict__ p, long long n, unsigned* __restrict__ out) {
    unsigned mx = 0u;
    for (long long i = blockIdx.x * 256ll + threadIdx.x; i < n; i += (long long)gridDim.x * 256)
        mx = max(mx, __float_as_uint(p[i]) & 0x7fffffffu);
#pragma unroll
    for (int off = 32; off > 0; off >>= 1)
        mx = max(mx, (unsigned)__shfl_xor((int)mx, off));
    if ((threadIdx.x & 63) == 0) atomicMax(out, mx);
}

__global__ void prep_kernel(int* __restrict__ flags) {
    if (threadIdx.x == 0) {
        unsigned ax = (unsigned)flags[3], aw = (unsigned)flags[4];
        flags[1] = (int)((ax >> 23) & 255u) - 127 + 2;   // EA
        flags[2] = (int)((aw >> 23) & 255u) - 127 + 2;   // EB
    }
}

// slice x (ONE batch) -> xs[c16][pix][6][16] i8 digits (digit chain R9-proven;
// layout changed so a lane's 6 fragments are 96 contiguous bytes)
__global__ __launch_bounds__(256) void slice_x_kernel(
    const float* __restrict__ x, const int* __restrict__ flags,
    int batch, signed char* __restrict__ xs) {
    if (flags[0] != 1) return;
    const int EA = flags[1];
    const float sA = __int_as_float((127 - EA) << 23);   // exact 2^-EA
    const int pix = blockIdx.x * 256 + threadIdx.x;
    const int c16 = blockIdx.y;
    if (pix >= NPIX) return;
    unsigned wds[6][4];
#pragma unroll
    for (int s = 0; s < 6; ++s)
#pragma unroll
        for (int dw = 0; dw < 4; ++dw) wds[s][dw] = 0u;
    const float* ap = x + ((size_t)(batch * CIN + c16 * 16)) * NPIX + pix;
#pragma unroll
    for (int t = 0; t < 16; ++t) {
        float u = ap[(size_t)t * NPIX] * sA;
#pragma unroll
        for (int s = 0; s < 6; ++s) {
            u *= 128.f;
            float dd = rintf(u);
            u -= dd;
            wds[s][t >> 2] |= ((unsigned)((int)dd & 0xff)) << ((t & 3) * 8);
        }
    }
    signed char* dst = xs + ((size_t)(c16 * NPIX + pix) * 6) * 16;
#pragma unroll
    for (int s = 0; s < 6; ++s)
        *(i32x4*)(dst + s * 16) =
            (i32x4){(int)wds[s][0], (int)wds[s][1], (int)wds[s][2], (int)wds[s][3]};
}

// slice W_conv -> ws8[s][co][k] i8 (5 digits), k=(kh*3+kw)*1024+ci  (R9-proven)
__global__ void slice_w_kernel(const float* __restrict__ W, const int* __restrict__ flags,
                               signed char* __restrict__ ws8) {
    if (flags[0] != 1) return;
    const int EB = flags[2];
    long long gid = blockIdx.x * 256ll + threadIdx.x;
    if (gid >= (long long)CMID * K_TOT) return;
    int co = (int)(gid / K_TOT);
    int k = (int)(gid - (long long)co * K_TOT);
    int pl = k >> 10, ci = k & 1023;
    double u = ldexp((double)W[((size_t)co * CIN + ci) * 9 + pl], -EB);
#pragma unroll
    for (int s = 0; s < 5; ++s) {
        u *= 128.0; double d = rint(u); u -= d;
        ws8[(size_t)s * (512ll * K_TOT) + (size_t)co * K_TOT + k] = (signed char)(int)d;
    }
}

// ---------------------------------------------------------------------------
// i8-Ozaki conv, TWO batches per launch. Grid (16 n-tiles, 19 m-blocks, 2 z).
// Block: 4 waves stacked m, wave tile 32m x 32n (R10-proven mapping).
// B staged in LDS (10KB/kc, double-buffered, 1 barrier/kc): block reads its
// B-slice once per kc (was 4x per wave). A fragments: 96 contiguous bytes.
// Stage/fragment equivalence: LDS[j][col][gB*16] <-> ws8[(j*512+n0+col)*K_TOT
// + pl*1024 + (kc&15)*64 + gB*16]  (col = ct*16+cB), identical bytes to the
// R10-proven direct reads.
// ---------------------------------------------------------------------------
__global__ __launch_bounds__(256, 2) void conv3x3_i8c(
    const signed char* __restrict__ xs, const signed char* __restrict__ ws8,
    const float* __restrict__ bconv, const int* __restrict__ flags,
    const int* __restrict__ itab, double* __restrict__ featB2) {
    if (flags[0] != 1) return;
    const int EA = flags[1], EB = flags[2];
    __shared__ signed char Bsm[2 * 12800];       // 2 bufs x 5s x 32col x 80B
    const int tid = threadIdx.x;
    const int l = tid & 63, w = tid >> 6;
    const int n0 = blockIdx.x * 32;
    const int mbase = blockIdx.y * 128 + w * 32;
    const int z = blockIdx.z;
    const signed char* xsb = xs + (size_t)z * XS_BATCH;

    const int rA = itab[l];
    const int gA = itab[64 + l];
    const int gB = itab[128 + l];
    const int cB = itab[192 + l];
    int dR[4], dC[4];
#pragma unroll
    for (int r = 0; r < 4; ++r) { dR[r] = itab[256 + l * 4 + r]; dC[r] = itab[512 + l * 4 + r]; }

    int yyr[2], xxr[2]; bool vmr[2];
#pragma unroll
    for (int rt = 0; rt < 2; ++rt) {
        int m = mbase + rt * 16 + rA;
        vmr[rt] = (m < NPIX);
        int mm = vmr[rt] ? m : 0;
        yyr[rt] = mm / FWW;
        xxr[rt] = mm - yyr[rt] * FWW;
    }

    // stage roles (constant per thread): u0=tid, u1=tid+256, u2=tid+512(<640)
    const int u0 = tid, u1 = tid + 256, u2 = tid + 512;
    const int s0 = u0 >> 7, c0 = (u0 & 127) >> 2, g0 = u0 & 3;
    const int s1 = u1 >> 7, c1 = (u1 & 127) >> 2, g1 = u1 & 3;
    const int s2 = u2 >> 7, c2 = (u2 & 127) >> 2, g2 = u2 & 3;
    const bool do2 = (u2 < 640);
    const signed char* gp0 = ws8 + ((size_t)(s0 * 512 + n0 + c0)) * K_TOT + g0 * 16;
    const signed char* gp1 = ws8 + ((size_t)(s1 * 512 + n0 + c1)) * K_TOT + g1 * 16;
    const signed char* gp2 = ws8 + ((size_t)(s2 * 512 + n0 + c2)) * K_TOT + g2 * 16;
    const int ld0 = s0 * 2560 + c0 * 80 + g0 * 16;
    const int ld1 = s1 * 2560 + c1 * 80 + g1 * 16;
    const int ld2 = s2 * 2560 + c2 * 80 + g2 * 16;
    // lane fragment LDS offsets
    const int fb0 = cB * 80 + gB * 16;
    const int fb1 = (16 + cB) * 80 + gB * 16;

    i32x4 acc[6][2][2];
#pragma unroll
    for (int s = 0; s < 6; ++s)
#pragma unroll
        for (int rt = 0; rt < 2; ++rt)
#pragma unroll
            for (int ct = 0; ct < 2; ++ct) acc[s][rt][ct] = (i32x4){0, 0, 0, 0};

#define KOFS(KC) ((size_t)((KC) >> 4) * 1024 + (size_t)(((KC) & 15) << 6))

    i32x4 sv0, sv1, sv2;
    {   // prologue: stage kc=0 into buf0
        size_t kofs = KOFS(0);
        sv0 = *(const i32x4*)(gp0 + kofs);
        sv1 = *(const i32x4*)(gp1 + kofs);
        if (do2) sv2 = *(const i32x4*)(gp2 + kofs);
        *(i32x4*)&Bsm[ld0] = sv0;
        *(i32x4*)&Bsm[ld1] = sv1;
        if (do2) *(i32x4*)&Bsm[ld2] = sv2;
    }
    __syncthreads();

    for (int kc = 0; kc < 144; ++kc) {
        const int cur = kc & 1;
        // issue next-tile B loads (global only)
        if (kc + 1 < 144) {
            size_t kofs = KOFS(kc + 1);
            sv0 = *(const i32x4*)(gp0 + kofs);
            sv1 = *(const i32x4*)(gp1 + kofs);
            if (do2) sv2 = *(const i32x4*)(gp2 + kofs);
        }
        // A fragments for current kc (96 contiguous bytes per rt)
        const int pl = kc >> 4;
        const int kh = pl / 3, kw2 = pl - kh * 3;
        const int c16 = ((kc & 15) << 2) + gA;
        i32x4 af[6][2];
#pragma unroll
        for (int rt = 0; rt < 2; ++rt) {
            const int iy = yyr[rt] + kh - 1, ix = xxr[rt] + kw2 - 1;
            const bool ok = vmr[rt] && iy >= 0 && iy < FHH && ix >= 0 && ix < FWW;
            const int pix = ok ? (iy * FWW + ix) : 0;
            const signed char* ap = xsb + ((size_t)(c16 * NPIX + pix) * 6) * 16;
#pragma unroll
            for (int s = 0; s < 6; ++s) {
                i32x4 v = *(const i32x4*)(ap + s * 16);
                if (!ok) v = (i32x4){0, 0, 0, 0};
                af[s][rt] = v;
            }
        }
        // MFMAs on staged buffer
        const signed char* bb = &Bsm[cur * 12800];
#pragma unroll
        for (int j = 0; j < 5; ++j) {
            i32x4 bf0 = *(const i32x4*)(bb + j * 2560 + fb0);
            i32x4 bf1 = *(const i32x4*)(bb + j * 2560 + fb1);
#pragma unroll
            for (int i = 0; i + j <= 5; ++i) {
                acc[i + j][0][0] = __builtin_amdgcn_mfma_i32_16x16x64_i8(af[i][0], bf0, acc[i + j][0][0], 0, 0, 0);
                acc[i + j][0][1] = __builtin_amdgcn_mfma_i32_16x16x64_i8(af[i][0], bf1, acc[i + j][0][1], 0, 0, 0);
                acc[i + j][1][0] = __builtin_amdgcn_mfma_i32_16x16x64_i8(af[i][1], bf0, acc[i + j][1][0], 0, 0, 0);
                acc[i + j][1][1] = __builtin_amdgcn_mfma_i32_16x16x64_i8(af[i][1], bf1, acc[i + j][1][1], 0, 0, 0);
            }
        }
        // write staged regs -> other buffer, one barrier per kc
        if (kc + 1 < 144) {
            signed char* bw = &Bsm[(cur ^ 1) * 12800];
            *(i32x4*)&bw[ld0] = sv0;
            *(i32x4*)&bw[ld1] = sv1;
            if (do2) *(i32x4*)&bw[ld2] = sv2;
        }
        __syncthreads();
    }
#undef KOFS

    double sc[6];
#pragma unroll
    for (int s = 0; s < 6; ++s) sc[s] = ldexp(1.0, EA + EB - 7 * (s + 2));
#pragma unroll
    for (int rt = 0; rt < 2; ++rt)
#pragma unroll
        for (int ct = 0; ct < 2; ++ct)
#pragma unroll
            for (int r = 0; r < 4; ++r) {
                int grow = mbase + rt * 16 + dR[r];
                int gcol = n0 + ct * 16 + dC[r];
                if (grow < NPIX) {
                    double v = (double)bconv[gcol];
#pragma unroll
                    for (int s = 0; s < 6; ++s) v += sc[s] * (double)acc[s][rt][ct][r];
                    featB2[((size_t)(z * NPIX + grow)) * CMID + gcol] = fmax(v, 0.0);
                }
            }
}

// K0: W_conv -> Wt[k][co] fp32 (fallback)
__global__ void wt3x3_kernel(const float* __restrict__ W, float* __restrict__ Wt) {
    int gid = blockIdx.x * 256 + threadIdx.x;
    if (gid >= K_TOT * CMID) return;
    int co = gid & 511;
    int k  = gid >> 9;
    int pl = k >> 10;
    int ci = k & 1023;
    Wt[gid] = W[((size_t)co * CIN + ci) * 9 + pl];
}

__global__ void wt1x1_kernel(const float* __restrict__ Wc, const float* __restrict__ Wb,
                             double* __restrict__ Wt2pD) {
    int gid = blockIdx.x * 256 + threadIdx.x;
    if (gid >= CMID * 64) return;
    int n = gid & 63, k = gid >> 6;
    double v = 0.0;
    if (n < 18)      v = (double)Wc[(size_t)n * CMID + k];
    else if (n < 54) v = (double)Wb[(size_t)(n - 18) * CMID + k];
    Wt2pD[gid] = v;
}

// Fallback f64 MFMA conv (R6-verified), runs only when flags[0]==0
#define ASZ (32 * 72)
__global__ __launch_bounds__(256, 4) void conv3x3_mfma(
    const float* __restrict__ x, const float* __restrict__ Wt,
    const float* __restrict__ bconv, const int* __restrict__ tab,
    const int* __restrict__ flags, double* __restrict__ feat) {
    if (flags[0] == 1) return;
    __shared__ float As[2 * ASZ];
    __shared__ float Bs[2 * ASZ];
    const int tid = threadIdx.x;
    const int lane = tid & 63;
    const int wave = tid >> 6;
    const int wm = wave >> 1;
    const int wn = wave & 1;
    const int n0 = blockIdx.x * 64;
    const int m0 = blockIdx.y * 64;

    const int aRow = tab[lane];
    const int aK   = tab[64 + lane];
    const int bK   = tab[128 + lane];
    const int bCol = tab[192 + lane];
    int dRow[4], dCol[4];
#pragma unroll
    for (int r = 0; r < 4; ++r) {
        dRow[r] = tab[256 + lane * 4 + r];
        dCol[r] = tab[512 + lane * 4 + r];
    }
    const int mm = tid & 63;
    const int t6 = tid >> 6;
    const int m = m0 + mm;
    const bool vm = (m < M_TOT);
    int b = 0, yy = 0, xx = 0;
    if (vm) { b = m / NPIX; int r = m - b * NPIX; yy = r / FWW; xx = r - yy * FWW; }
    const int bk2 = tid >> 4;
    const int bn2 = (tid & 15) << 2;

    f64x4 acc[2][2];
#pragma unroll
    for (int i = 0; i < 2; ++i)
#pragma unroll
        for (int j = 0; j < 2; ++j) acc[i][j] = (f64x4){0.0, 0.0, 0.0, 0.0};

    const float* aBase = &As[aK * 72 + wm * 32 + aRow];
    const float* bBase = &Bs[bK * 72 + wn * 32 + bCol];

#define STAGE_REGS(KC, VA, VB0, VB1) do {                                     \
        const int pl_ = (KC) >> 5;                                            \
        const int kh_ = pl_ / 3, kw_ = pl_ - kh_ * 3;                         \
        const int ci0_ = ((KC) & 31) << 5;                                    \
        const int iy_ = yy + kh_ - 1, ix_ = xx + kw_ - 1;                     \
        const bool ok_ = vm && (iy_ >= 0) && (iy_ < FHH) && (ix_ >= 0) && (ix_ < FWW); \
        const float* ap_ = x + ((size_t)(b * CIN + ci0_ + t6)) * NPIX + iy_ * FWW + ix_; \
        _Pragma("unroll")                                                     \
        for (int r = 0; r < 8; ++r) {                                         \
            float v_ = 0.f;                                                   \
            if (ok_) v_ = ap_[(size_t)r * 4 * NPIX];                          \
            VA[r] = v_;                                                       \
        }                                                                     \
        const float4* wp_ = (const float4*)(Wt + (size_t)(((KC) << 5) + bk2) * CMID + n0 + bn2); \
        VB0 = wp_[0];                                                         \
        VB1 = wp_[2048];                                                      \
    } while (0)

#define WRITE_TILE(BUF, VA, VB0, VB1) do {                                    \
        _Pragma("unroll")                                                     \
        for (int r = 0; r < 8; ++r)                                           \
            As[(BUF) * ASZ + (t6 + r * 4) * 72 + mm] = VA[r];                 \
        *(float4*)&Bs[(BUF) * ASZ + bk2 * 72 + bn2] = VB0;                    \
        *(float4*)&Bs[(BUF) * ASZ + (bk2 + 16) * 72 + bn2] = VB1;             \
    } while (0)

#define MFMA_PHASE(BUF) do {                                                  \
        _Pragma("unroll")                                                     \
        for (int ks = 0; ks < 8; ++ks) {                                      \
            double a0 = (double)aBase[(BUF) * ASZ + ks * 288];                \
            double a1 = (double)aBase[(BUF) * ASZ + ks * 288 + 16];           \
            double b0 = (double)bBase[(BUF) * ASZ + ks * 288];                \
            double b1 = (double)bBase[(BUF) * ASZ + ks * 288 + 16];           \
            acc[0][0] = __builtin_amdgcn_mfma_f64_16x16x4f64(a0, b0, acc[0][0], 0, 0, 0); \
            acc[0][1] = __builtin_amdgcn_mfma_f64_16x16x4f64(a0, b1, acc[0][1], 0, 0, 0); \
            acc[1][0] = __builtin_amdgcn_mfma_f64_16x16x4f64(a1, b0, acc[1][0], 0, 0, 0); \
            acc[1][1] = __builtin_amdgcn_mfma_f64_16x16x4f64(a1, b1, acc[1][1], 0, 0, 0); \
        }                                                                     \
    } while (0)

    float va[8]; float4 vb0, vb1;
    float wa[8]; float4 wb0, wb1;
    STAGE_REGS(0, va, vb0, vb1);
    WRITE_TILE(0, va, vb0, vb1);
    __syncthreads();
    for (int kc = 0; kc < 288; kc += 2) {
        STAGE_REGS(kc + 1, wa, wb0, wb1);
        MFMA_PHASE(0);
        WRITE_TILE(1, wa, wb0, wb1);
        __syncthreads();
        if (kc + 2 < 288) {
            STAGE_REGS(kc + 2, va, vb0, vb1);
            MFMA_PHASE(1);
            WRITE_TILE(0, va, vb0, vb1);
            __syncthreads();
        } else {
            MFMA_PHASE(1);
        }
    }
#undef STAGE_REGS
#undef WRITE_TILE
#undef MFMA_PHASE
#pragma unroll
    for (int mi = 0; mi < 2; ++mi)
#pragma unroll
        for (int nj = 0; nj < 2; ++nj)
#pragma unroll
            for (int r = 0; r < 4; ++r) {
                int mg  = m0 + wm * 32 + mi * 16 + dRow[r];
                int col = n0 + wn * 32 + nj * 16 + dCol[r];
                if (mg < M_TOT)
                    feat[(size_t)mg * CMID + col] =
                        fmax(acc[mi][nj][r] + (double)bconv[col], 0.0);
            }
}

// K2a: 1x1 convs for ONE batch pair (i8 mode). featB2 = 4788 rows.
__global__ __launch_bounds__(256) void conv1x1_i8(
    const double* __restrict__ featB2, const double* __restrict__ Wt2pD,
    const float* __restrict__ bcls, const float* __restrict__ bbx,
    const int* __restrict__ flags, int pair, double* __restrict__ out54) {
    if (flags[0] != 1) return;
    __shared__ double As[4 * 512];
    __shared__ double Bsh[64 * 64];
    int tid = threadIdx.x;
    int m0 = blockIdx.x * 4;                   // local row in [0, 4788)
    for (int off = tid; off < 2048; off += 256) As[off] = featB2[(size_t)m0 * CMID + off];
    int p = tid >> 6, n = tid & 63;
    double acc = 0.0;
    for (int c = 0; c < 8; ++c) {
        __syncthreads();
        for (int off = tid; off < 4096; off += 256) Bsh[off] = Wt2pD[c * 4096 + off];
        __syncthreads();
        const double* ap = &As[p * 512 + c * 64];
#pragma unroll 8
        for (int k2 = 0; k2 < 64; ++k2) acc = fma(ap[k2], Bsh[k2 * 64 + n], acc);
    }
    if (n < 54) {
        double bias = (double)((n < 18) ? bcls[n] : bbx[n - 18]);
        out54[((size_t)(pair * 4788 + m0 + p)) * 64 + n] = acc + bias;
    }
}

// K2b: 1x1 convs, fallback mode (full featD)
__global__ __launch_bounds__(256) void conv1x1_fb(
    const double* __restrict__ feat, const double* __restrict__ Wt2pD,
    const float* __restrict__ bcls, const float* __restrict__ bbx,
    const int* __restrict__ flags, double* __restrict__ out54) {
    if (flags[0] == 1) return;
    __shared__ double As[4 * 512];
    __shared__ double Bsh[64 * 64];
    int tid = threadIdx.x;
    int m0 = blockIdx.x * 4;
    for (int off = tid; off < 2048; off += 256) As[off] = feat[(size_t)m0 * CMID + off];
    int p = tid >> 6, n = tid & 63;
    double acc = 0.0;
    for (int c = 0; c < 8; ++c) {
        __syncthreads();
        for (int off = tid; off < 4096; off += 256) Bsh[off] = Wt2pD[c * 4096 + off];
        __syncthreads();
        const double* ap = &As[p * 512 + c * 64];
#pragma unroll 8
        for (int k2 = 0; k2 < 64; ++k2) acc = fma(ap[k2], Bsh[k2 * 64 + n], acc);
    }
    if (n < 54) {
        double bias = (double)((n < 18) ? bcls[n] : bbx[n - 18]);
        out54[(size_t)(m0 + p) * 64 + n] = acc + bias;
    }
}

// K2c: softmax-pair + bbox decode + clip, fp64
__global__ void proposals_kernel(const double* __restrict__ out54, const float* __restrict__ iminfo,
                                 double* __restrict__ scoresD, double* __restrict__ propsD) {
    int gid = blockIdx.x * 256 + threadIdx.x;
    if (gid >= BATCH * NSC) return;
    int b = gid / NSC;
    int rem = gid - b * NSC;
    int p = rem / 9;
    int a = rem - p * 9;
    int y = p / FWW, x = p - y * FWW;
    int m = b * NPIX + p;
    const double* row = out54 + (size_t)m * 64;
    double s0 = row[a], s1 = row[9 + a];
    double mx = fmax(s0, s1);
    double e0 = exp(s0 - mx), e1 = exp(s1 - mx);
    scoresD[gid] = e1 / (e0 + e1);
    double dx = row[18 + 4 * a], dy = row[19 + 4 * a], dw = row[20 + 4 * a], dh = row[21 + 4 * a];
    double ax1 = x * 16.0 + ANCX1[a], ay1 = y * 16.0 + ANCY1[a];
    double ax2 = x * 16.0 + ANCX2[a], ay2 = y * 16.0 + ANCY2[a];
    double w = ax2 - ax1 + 1.0, h = ay2 - ay1 + 1.0;
    double cx = ax1 + 0.5 * w, cy = ay1 + 0.5 * h;
    double px = dx * w + cx, py = dy * h + cy;
    double pw = exp(dw) * w, ph = exp(dh) * h;
    double imh = (double)iminfo[b * 3 + 0], imw = (double)iminfo[b * 3 + 1];
    double x1 = fmin(fmax(px - 0.5 * pw, 0.0), imw - 1.0);
    double y1 = fmin(fmax(py - 0.5 * ph, 0.0), imh - 1.0);
    double x2 = fmin(fmax(px + 0.5 * pw, 0.0), imw - 1.0);
    double y2 = fmin(fmax(py + 0.5 * ph, 0.0), imh - 1.0);
    double* o = propsD + (size_t)gid * 4;
    o[0] = x1; o[1] = y1; o[2] = x2; o[3] = y2;
}

// K3: exact top-2000 radix-select + bitonic
__global__ __launch_bounds__(256) void select_kernel(const double* __restrict__ scoresD,
                                                     const double* __restrict__ propsD,
                                                     double* __restrict__ boxesD) {
    __shared__ unsigned int hist4[4][256];
    __shared__ unsigned int histf[256];
    __shared__ unsigned long long keys[2048];
    __shared__ unsigned long long sh_thr;
    __shared__ int sh_need;
    __shared__ int cnt;
    const int b = blockIdx.x, tid = threadIdx.x;
    const int w4 = tid >> 6;
    const double* sc = scoresD + (size_t)b * NSC;

    unsigned long long prefix = 0ull;
    int need = PRE_N;
    for (int d = 7; d >= 0; --d) {
        for (int z = tid; z < 1024; z += 256) ((unsigned int*)hist4)[z] = 0u;
        __syncthreads();
        const int shift = d * 8;
        const unsigned long long maskAbove = (d == 7) ? 0ull : (~0ull << (shift + 8));
        for (int i = tid; i < NSC; i += 256) {
            unsigned long long sb = (unsigned long long)__double_as_longlong(sc[i]);
            unsigned long long key = (sb & ~0x7FFFull) | (unsigned long long)((~i) & 0x7FFF);
            if (((key ^ prefix) & maskAbove) == 0ull)
                atomicAdd(&hist4[w4][(unsigned int)(key >> shift) & 255u], 1u);
        }
        __syncthreads();
        histf[tid] = hist4[0][tid] + hist4[1][tid] + hist4[2][tid] + hist4[3][tid];
        __syncthreads();
        if (tid == 0) {
            int acc = 0, v = 255;
            for (; v > 0; --v) {
                int c = (int)histf[v];
                if (acc + c >= need) break;
                acc += c;
            }
            sh_thr = prefix | ((unsigned long long)(unsigned int)v << shift);
            sh_need = need - acc;
        }
        __syncthreads();
        prefix = sh_thr;
        need = sh_need;
        __syncthreads();
    }
    if (tid == 0) cnt = 0;
    __syncthreads();
    for (int i = tid; i < NSC; i += 256) {
        unsigned long long sb = (unsigned long long)__double_as_longlong(sc[i]);
        unsigned long long key = (sb & ~0x7FFFull) | (unsigned long long)((~i) & 0x7FFF);
        if (key >= prefix) {
            int slot = atomicAdd(&cnt, 1);
            if (slot < 2048) keys[slot] = key;
        }
    }
    __syncthreads();
    int c0 = cnt;
    for (int i = tid; i < 2048; i += 256)
        if (i >= c0) keys[i] = 0ull;
    for (int k2 = 2; k2 <= 2048; k2 <<= 1)
        for (int j = k2 >> 1; j > 0; j >>= 1) {
            __syncthreads();
            for (int i = tid; i < 2048; i += 256) {
                int l = i ^ j;
                if (l > i) {
                    unsigned long long a = keys[i], c = keys[l];
                    bool up = (i & k2) == 0;
                    if (up ? (a < c) : (a > c)) { keys[i] = c; keys[l] = a; }
                }
            }
        }
    __syncthreads();
    const double* pr = propsD + (size_t)b * NSC * 4;
    double* bs = boxesD + (size_t)b * PRE_N * 4;
    for (int r = tid; r < PRE_N; r += 256) {
        int idx = (int)((~keys[r]) & 0x7FFF);
        if (idx >= NSC) idx = 0;
        bs[r * 4 + 0] = pr[(size_t)idx * 4 + 0];
        bs[r * 4 + 1] = pr[(size_t)idx * 4 + 1];
        bs[r * 4 + 2] = pr[(size_t)idx * 4 + 2];
        bs[r * 4 + 3] = pr[(size_t)idx * 4 + 3];
    }
}

// K4a: fp64 IoU suppression bitmask
__global__ __launch_bounds__(256) void iou_mask_kernel(const double* __restrict__ boxesD,
                                                       unsigned long long* __restrict__ supmask) {
    __shared__ double bx[PRE_N * 4];
    int b = blockIdx.x;
    int i0 = blockIdx.y * 80;
    const double* src = boxesD + (size_t)b * PRE_N * 4;
    for (int o = threadIdx.x; o < PRE_N * 4; o += 256) bx[o] = src[o];
    __syncthreads();
    int ty = threadIdx.x >> 5, jw = threadIdx.x & 31;
    for (int ii = ty; ii < 80; ii += 8) {
        int i = i0 + ii;
        double bix1 = bx[i * 4 + 0], biy1 = bx[i * 4 + 1], bix2 = bx[i * 4 + 2], biy2 = bx[i * 4 + 3];
        double areai = (bix2 - bix1 + 1.0) * (biy2 - biy1 + 1.0);
        unsigned long long bits = 0ull;
        for (int t = 0; t < 64; ++t) {
            int j = t * 32 + jw;
            if (j > i && j < PRE_N) {
                double bjx1 = bx[j * 4 + 0], bjy1 = bx[j * 4 + 1], bjx2 = bx[j * 4 + 2], bjy2 = bx[j * 4 + 3];
                double iw = fmin(bix2, bjx2) - fmax(bix1, bjx1) + 1.0; iw = fmax(iw, 0.0);
                double ih = fmin(biy2, bjy2) - fmax(biy1, bjy1) + 1.0; ih = fmax(ih, 0.0);
                double inter = iw * ih;
                double areaj = (bjx2 - bjx1 + 1.0) * (bjy2 - bjy1 + 1.0);
                double iou = inter / (areai + areaj - inter);
                if (iou > 0.7) bits |= (1ull << t);
            }
        }
        supmask[((size_t)b * PRE_N + i) * 32 + jw] = bits;
    }
}

// K4b: greedy suppression + first-300 + fp32 output
__global__ void nms_final_kernel(const unsigned long long* __restrict__ supmask,
                                 const double* __restrict__ boxesD,
                                 float* __restrict__ out) {
    int b = blockIdx.x;
    int lane = threadIdx.x;
    int w = lane & 31;
    const unsigned long long* mask = supmask + (size_t)b * PRE_N * 32;
    int nbits = (w < 16) ? 63 : 62;
    unsigned long long kw = (1ull << nbits) - 1ull;
    unsigned long long rr[16];
#pragma unroll
    for (int d2 = 0; d2 < 16; ++d2) rr[d2] = mask[d2 * 32 + w];
    for (int i = 0; i < PRE_N; i += 16) {
#pragma unroll
        for (int u2 = 0; u2 < 16; ++u2) {
            int ii = i + u2;
            unsigned long long rcur = rr[u2];
            int ip = ii + 16;
            rr[u2] = (ip < PRE_N) ? mask[ip * 32 + w] : 0ull;
            unsigned long long kword = __shfl(kw, ii & 31);
            if ((kword >> (ii >> 5)) & 1ull) kw &= ~rcur;
        }
    }
    __shared__ unsigned long long keepw[32];
    __shared__ int pos[POST_N];
    if (lane < 32) keepw[lane] = kw;
    __syncthreads();
    if (lane == 0) {
        int c2 = 0;
        for (int j = 0; j < PRE_N && c2 < POST_N; ++j)
            if ((keepw[j & 31] >> (j >> 5)) & 1ull) pos[c2++] = j;
        for (int j = 0; j < PRE_N && c2 < POST_N; ++j)
            if (!((keepw[j & 31] >> (j >> 5)) & 1ull)) pos[c2++] = j;
    }
    __syncthreads();
    for (int r = lane; r < POST_N; r += 64) {
        int p = pos[r];
        const double* bxp = boxesD + ((size_t)b * PRE_N + p) * 4;
        float* o = out + ((size_t)b * POST_N + r) * 5;
        o[0] = (float)b; o[1] = (float)bxp[0]; o[2] = (float)bxp[1];
        o[3] = (float)bxp[2]; o[4] = (float)bxp[3];
    }
    if (b == 0 && lane == 0) { out[BATCH * POST_N * 5] = 0.f; out[BATCH * POST_N * 5 + 1] = 0.f; }
}

extern "C" void kernel_launch(void* const* d_in, const int* in_sizes, int n_in,
                              void* d_out, int out_size, void* d_ws, size_t ws_size,
                              hipStream_t stream) {
    (void)in_sizes; (void)n_in; (void)out_size;
    const float* base_feat = (const float*)d_in[0];
    const float* im_info   = (const float*)d_in[1];
    const float* W_conv    = (const float*)d_in[4];
    const float* b_conv    = (const float*)d_in[5];
    const float* W_cls     = (const float*)d_in[6];
    const float* b_cls     = (const float*)d_in[7];
    const float* W_bbox    = (const float*)d_in[8];
    const float* b_bbox    = (const float*)d_in[9];
    float* out = (float*)d_out;

    // Layout (total 118,740,096 B == R9/R10/R11-proven gate).
    // Region R0 [0, 78,446,592): i8 mode = xsA|xsB|featB2 (49 MB used);
    //                            fallback = full featD (78.4 MB). Mutually exclusive.
    char* W = (char*)d_ws;
    signed char* xsA = (signed char*)W;                   // 14,708,736
    double* featB2   = (double*)(W + 29417472);           // 19,611,648 (pair buffer)
    double* featD    = (double*)W;                        // fallback full
    float*  Wt       = (float*)(W + 78446592);            // 18,874,368 (fallback)
    signed char* ws8 = (signed char*)(W + 78446592);      // 23,592,960 (i8, clobbers Wt)
    double* out54D   = (double*)(W + 102039552);          // 9,805,824
    double* scoresD  = (double*)(W + 111845376);          // 1,378,944
    double* propsD   = (double*)(W + 113224320);          // 5,515,776 -> 118,740,096
    // tails carved from propsD head (props written later by proposals — disjoint):
    double* Wt2pD    = (double*)(W + 113224320);          // 262,144
    int*    tab      = (int*)(W + 113486464);             // 3,072
    int*    itab     = (int*)(W + 113489536);             // 3,072
    int*    iflags   = (int*)(W + 113492608);             // 64
    unsigned long long* supmask = (unsigned long long*)W; // R0 dead after conv1x1
    double* boxesD   = scoresD;                           // written at end of select

    bool i8cap = (ws_size >= 118740096ull);

    flaginit_kernel<<<1, 64, 0, stream>>>(iflags);
    mfma_probe_kernel<<<1, 64, 0, stream>>>(tab);
    if (i8cap) {
        i8_probe_kernel<<<1, 64, 0, stream>>>(itab, iflags);
        maxabs_kernel<<<1024, 256, 0, stream>>>(base_feat, (long long)BATCH * CIN * NPIX,
                                                (unsigned*)&iflags[3]);
        maxabs_kernel<<<128, 256, 0, stream>>>(W_conv, (long long)CMID * CIN * 9,
                                               (unsigned*)&iflags[4]);
        prep_kernel<<<1, 64, 0, stream>>>(iflags);
    }
    wt3x3_kernel<<<(K_TOT * CMID + 255) / 256, 256, 0, stream>>>(W_conv, Wt);
    wt1x1_kernel<<<(CMID * 64 + 255) / 256, 256, 0, stream>>>(W_cls, W_bbox, Wt2pD);
    if (i8cap) {
        slice_w_kernel<<<(int)((4718592 + 255) / 256), 256, 0, stream>>>(W_conv, iflags, ws8);
        for (int pair = 0; pair < 4; ++pair) {
            slice_x_kernel<<<dim3(10, 64), 256, 0, stream>>>(base_feat, iflags, pair * 2, xsA);
            slice_x_kernel<<<dim3(10, 64), 256, 0, stream>>>(base_feat, iflags, pair * 2 + 1,
                                                             xsA + XS_BATCH);
            conv3x3_i8c<<<dim3(16, 19, 2), 256, 0, stream>>>(xsA, ws8, b_conv, iflags, itab,
                                                             featB2);
            conv1x1_i8<<<1197, 256, 0, stream>>>(featB2, Wt2pD, b_cls, b_bbox, iflags, pair,
                                                 out54D);
        }
    }
    conv3x3_mfma<<<dim3(8, 300), 256, 0, stream>>>(base_feat, Wt, b_conv, tab, iflags, featD);
    conv1x1_fb<<<M_TOT / 4, 256, 0, stream>>>(featD, Wt2pD, b_cls, b_bbox, iflags, out54D);
    proposals_kernel<<<(BATCH * NSC + 255) / 256, 256, 0, stream>>>(out54D, im_info, scoresD, propsD);
    select_kernel<<<BATCH, 256, 0, stream>>>(scoresD, propsD, boxesD);
    iou_mask_kernel<<<dim3(BATCH, 25), 256, 0, stream>>>(boxesD, supmask);
    nms_final_kernel<<<BATCH, 64, 0, stream>>>(supmask, boxesD, out);
}

// Round 13
// 3259.191 us; speedup vs baseline: 1.7473x; 1.1309x over previous
//
#include <hip/hip_runtime.h>

#define FHH 38
#define FWW 63
#define NPIX 2394        // 38*63
#define BATCH 8
#define CIN 1024
#define CMID 512
#define NSC 21546        // NPIX*9
#define M_TOT 19152      // BATCH*NPIX
#define K_TOT 9216       // CIN*9
#define PRE_N 2000
#define POST_N 300
#define XS_BATCH 14708736ll      // 64 c16 * 2394 pix * 96 B

typedef double f64x4 __attribute__((ext_vector_type(4)));
typedef int    i32x4 __attribute__((ext_vector_type(4)));

// exact anchors
__device__ const double ANCX1[9] = {-84.,-176.,-360.,-56.,-120.,-248.,-36.,-80.,-168.};
__device__ const double ANCY1[9] = {-40.,-88.,-184.,-56.,-120.,-248.,-80.,-168.,-344.};
__device__ const double ANCX2[9] = {99.,191.,375.,71.,135.,263.,51.,95.,183.};
__device__ const double ANCY2[9] = {55.,103.,199.,71.,135.,263.,95.,183.,359.};

__device__ __forceinline__ int h1f(int l, int t) { return ((l * 16 + t) * 37) % 61 - 30; }
__device__ __forceinline__ int h2f(int l, int t) { return ((l * 16 + t) * 53) % 59 - 29; }

// ---------------------------------------------------------------------------
// f64 MFMA layout probe (R4-verified; feeds the fallback conv)
// ---------------------------------------------------------------------------
__global__ void mfma_probe_kernel(int* __restrict__ tab) {
    const int l = threadIdx.x;
    __shared__ int aiS[64], bjS[64], kbS[64];
    const f64x4 zero = {0.0, 0.0, 0.0, 0.0};
    int di[4] = {-1, -1, -1, -1}, dj[4] = {-1, -1, -1, -1};
    int ai_l = 0, bj_l = 0, ka_l = 0;
    kbS[l] = 0x7fffffff;
    __syncthreads();
    const double bval = __longlong_as_double((long long)(1023 + l) << 52);
    for (int p = 0; p < 64; ++p) {
        double a = (l == p) ? 1.0 : 0.0;
        f64x4 d = __builtin_amdgcn_mfma_f64_16x16x4f64(a, bval, zero, 0, 0, 0);
        int lmin = 0x7fffffff, kmin = 0x7fffffff;
        bool lit[4]; int qv[4];
#pragma unroll
        for (int r = 0; r < 4; ++r) {
            lit[r] = (d[r] != 0.0);
            qv[r] = ((__double2hiint(d[r]) >> 20) & 0x7ff) - 1023;
            if (lit[r]) { lmin = min(lmin, di[r] < 0 ? p : di[r]); kmin = min(kmin, qv[r]); }
        }
#pragma unroll
        for (int off = 32; off > 0; off >>= 1) {
            lmin = min(lmin, __shfl_xor(lmin, off));
            kmin = min(kmin, __shfl_xor(kmin, off));
        }
#pragma unroll
        for (int r = 0; r < 4; ++r)
            if (lit[r]) { di[r] = lmin; atomicMin(&kbS[qv[r]], kmin); }
        if (l == p) { ai_l = lmin; ka_l = kmin; }
    }
    for (int q = 0; q < 64; ++q) {
        double b = (l == q) ? 1.0 : 0.0;
        f64x4 d = __builtin_amdgcn_mfma_f64_16x16x4f64(1.0, b, zero, 0, 0, 0);
        int lmin = 0x7fffffff;
        bool lit[4];
#pragma unroll
        for (int r = 0; r < 4; ++r) {
            lit[r] = (d[r] != 0.0);
            if (lit[r]) lmin = min(lmin, dj[r] < 0 ? q : dj[r]);
        }
#pragma unroll
        for (int off = 32; off > 0; off >>= 1) lmin = min(lmin, __shfl_xor(lmin, off));
#pragma unroll
        for (int r = 0; r < 4; ++r) if (lit[r]) dj[r] = lmin;
        if (l == q) bj_l = lmin;
    }
    aiS[l] = ai_l; bjS[l] = bj_l;
    __syncthreads();
    int kb_l = kbS[l];
    int a_row_rk = 0, a_k_rk = 0, b_k_rk = 0, b_col_rk = 0;
    for (int t = 0; t < 64; ++t) {
        a_row_rk += (aiS[t] == t && t < ai_l);
        b_col_rk += (bjS[t] == t && t < bj_l);
        a_k_rk   += (kbS[t] == t && t < ka_l);
        b_k_rk   += (kbS[t] == t && t < kb_l);
    }
    tab[l] = a_row_rk; tab[64 + l] = a_k_rk; tab[128 + l] = b_k_rk; tab[192 + l] = b_col_rk;
#pragma unroll
    for (int r = 0; r < 4; ++r) {
        int dr = 0, dc = 0;
        for (int t = 0; t < 64; ++t) {
            dr += (aiS[t] == t && t < di[r]);
            dc += (bjS[t] == t && t < dj[r]);
        }
        tab[256 + l * 4 + r] = dr;
        tab[512 + l * 4 + r] = dc;
    }
}

__global__ void flaginit_kernel(int* __restrict__ f) {
    if (threadIdx.x == 0) { f[0] = 0; f[1] = 0; f[2] = 0; f[3] = 0; f[4] = 0; }
}

// ---------------------------------------------------------------------------
// i8 MFMA probe + self-validation (R9-R12-verified on HW)
// ---------------------------------------------------------------------------
__global__ void i8_probe_kernel(int* __restrict__ itab, int* __restrict__ flags) {
    const int l = threadIdx.x;
    __shared__ int aiS[64], bjS[64], kbS[64];
    __shared__ int pOf[64], qOf[64];
    const i32x4 zero = {0, 0, 0, 0};
    const i32x4 ones = {0x01010101, 0x01010101, 0x01010101, 0x01010101};
    int di[4] = {-1, -1, -1, -1}, dj[4] = {-1, -1, -1, -1};
    int ai_l = -1, bj_l = -1, ka_l = -1;
    kbS[l] = 0x7fffffff; pOf[l] = 0; qOf[l] = 0;
    __syncthreads();

    for (int p = 0; p < 64; ++p) {
        i32x4 a = (l == p) ? ones : zero;
        i32x4 d = __builtin_amdgcn_mfma_i32_16x16x64_i8(a, ones, zero, 0, 0, 0);
        int lmin = 0x7fffffff;
        bool lit[4];
#pragma unroll
        for (int r = 0; r < 4; ++r) {
            lit[r] = (d[r] != 0);
            if (lit[r]) lmin = min(lmin, di[r] < 0 ? p : di[r]);
        }
#pragma unroll
        for (int off = 32; off > 0; off >>= 1) lmin = min(lmin, __shfl_xor(lmin, off));
#pragma unroll
        for (int r = 0; r < 4; ++r) if (lit[r]) di[r] = lmin;
        if (l == p) ai_l = lmin;
    }
    for (int q = 0; q < 64; ++q) {
        i32x4 b = (l == q) ? ones : zero;
        i32x4 d = __builtin_amdgcn_mfma_i32_16x16x64_i8(ones, b, zero, 0, 0, 0);
        int lmin = 0x7fffffff;
        bool lit[4];
#pragma unroll
        for (int r = 0; r < 4; ++r) {
            lit[r] = (d[r] != 0);
            if (lit[r]) lmin = min(lmin, dj[r] < 0 ? q : dj[r]);
        }
#pragma unroll
        for (int off = 32; off > 0; off >>= 1) lmin = min(lmin, __shfl_xor(lmin, off));
#pragma unroll
        for (int r = 0; r < 4; ++r) if (lit[r]) dj[r] = lmin;
        if (l == q) bj_l = lmin;
    }
    {
        unsigned bw = (unsigned)(l + 1);
        bw |= bw << 8; bw |= bw << 16;
        i32x4 bq = {(int)bw, (int)bw, (int)bw, (int)bw};
        for (int p = 0; p < 64; ++p) {
            i32x4 a = (l == p) ? ones : zero;
            i32x4 d = __builtin_amdgcn_mfma_i32_16x16x64_i8(a, bq, zero, 0, 0, 0);
            int kmin = 0x7fffffff;
            bool lit[4]; int qv[4];
#pragma unroll
            for (int r = 0; r < 4; ++r) {
                lit[r] = (d[r] != 0);
                qv[r] = d[r] / 16 - 1;
                if (lit[r]) kmin = min(kmin, qv[r]);
            }
#pragma unroll
            for (int off = 32; off > 0; off >>= 1) kmin = min(kmin, __shfl_xor(kmin, off));
#pragma unroll
            for (int r = 0; r < 4; ++r)
                if (lit[r] && qv[r] >= 0 && qv[r] < 64) atomicMin(&kbS[qv[r]], kmin);
            if (l == p) ka_l = kmin;
        }
    }
    aiS[l] = ai_l; bjS[l] = bj_l;
    __syncthreads();
    int kb_l = kbS[l];
    int rA = 0, gA = 0, gB = 0, cB = 0;
    for (int t = 0; t < 64; ++t) {
        rA += (aiS[t] == t && t < ai_l);
        cB += (bjS[t] == t && t < bj_l);
        gA += (kbS[t] == t && t < ka_l);
        gB += (kbS[t] == t && t < kb_l);
    }
    itab[l] = rA; itab[64 + l] = gA; itab[128 + l] = gB; itab[192 + l] = cB;
    int dR[4], dC[4];
#pragma unroll
    for (int r = 0; r < 4; ++r) {
        int dr = 0, dc = 0;
        for (int t = 0; t < 64; ++t) {
            dr += (aiS[t] == t && t < di[r]);
            dc += (bjS[t] == t && t < dj[r]);
        }
        dR[r] = dr; dC[r] = dc;
        itab[256 + l * 4 + r] = dr;
        itab[512 + l * 4 + r] = dc;
    }
    __syncthreads();
    bool ok = (rA < 16) && (gA < 4) && (cB < 16) && (gB < 4);
    if (ok) { pOf[rA * 4 + gA] = l; qOf[cB * 4 + gB] = l; }
    __syncthreads();
    unsigned wa[4], wb[4];
#pragma unroll
    for (int dw = 0; dw < 4; ++dw) {
        unsigned a = 0, b = 0;
#pragma unroll
        for (int by = 0; by < 4; ++by) {
            int t = dw * 4 + by;
            a |= ((unsigned)(h1f(l, t) & 0xff)) << (8 * by);
            b |= ((unsigned)(h2f(l, t) & 0xff)) << (8 * by);
        }
        wa[dw] = a; wb[dw] = b;
    }
    i32x4 va = {(int)wa[0], (int)wa[1], (int)wa[2], (int)wa[3]};
    i32x4 vb = {(int)wb[0], (int)wb[1], (int)wb[2], (int)wb[3]};
    i32x4 d = __builtin_amdgcn_mfma_i32_16x16x64_i8(va, vb, zero, 0, 0, 0);
#pragma unroll
    for (int r = 0; r < 4; ++r) {
        if (dR[r] >= 16 || dC[r] >= 16) { ok = false; continue; }
        int ref = 0;
        for (int g = 0; g < 4; ++g) {
            int p = pOf[dR[r] * 4 + g], q = qOf[dC[r] * 4 + g];
            for (int t = 0; t < 16; ++t) ref += h1f(p, t) * h2f(q, t);
        }
        ok = ok && (d[r] == ref);
    }
    unsigned long long mb = __ballot(ok);
    if (l == 0) flags[0] = (mb == ~0ull) ? 1 : 0;
}

__global__ void maxabs_kernel(const float* __restrict__ p, long long n, unsigned* __restrict__ out) {
    unsigned mx = 0u;
    for (long long i = blockIdx.x * 256ll + threadIdx.x; i < n; i += (long long)gridDim.x * 256)
        mx = max(mx, __float_as_uint(p[i]) & 0x7fffffffu);
#pragma unroll
    for (int off = 32; off > 0; off >>= 1)
        mx = max(mx, (unsigned)__shfl_xor((int)mx, off));
    if ((threadIdx.x & 63) == 0) atomicMax(out, mx);
}

__global__ void prep_kernel(int* __restrict__ flags) {
    if (threadIdx.x == 0) {
        unsigned ax = (unsigned)flags[3], aw = (unsigned)flags[4];
        flags[1] = (int)((ax >> 23) & 255u) - 127 + 2;   // EA
        flags[2] = (int)((aw >> 23) & 255u) - 127 + 2;   // EB
    }
}

// slice x (ONE batch) -> xs[c16][pix][6][16] i8 digits (R12-proven)
__global__ __launch_bounds__(256) void slice_x_kernel(
    const float* __restrict__ x, const int* __restrict__ flags,
    int batch, signed char* __restrict__ xs) {
    if (flags[0] != 1) return;
    const int EA = flags[1];
    const float sA = __int_as_float((127 - EA) << 23);   // exact 2^-EA
    const int pix = blockIdx.x * 256 + threadIdx.x;
    const int c16 = blockIdx.y;
    if (pix >= NPIX) return;
    unsigned wds[6][4];
#pragma unroll
    for (int s = 0; s < 6; ++s)
#pragma unroll
        for (int dw = 0; dw < 4; ++dw) wds[s][dw] = 0u;
    const float* ap = x + ((size_t)(batch * CIN + c16 * 16)) * NPIX + pix;
#pragma unroll
    for (int t = 0; t < 16; ++t) {
        float u = ap[(size_t)t * NPIX] * sA;
#pragma unroll
        for (int s = 0; s < 6; ++s) {
            u *= 128.f;
            float dd = rintf(u);
            u -= dd;
            wds[s][t >> 2] |= ((unsigned)((int)dd & 0xff)) << ((t & 3) * 8);
        }
    }
    signed char* dst = xs + ((size_t)(c16 * NPIX + pix) * 6) * 16;
#pragma unroll
    for (int s = 0; s < 6; ++s)
        *(i32x4*)(dst + s * 16) =
            (i32x4){(int)wds[s][0], (int)wds[s][1], (int)wds[s][2], (int)wds[s][3]};
}

// slice W_conv -> ws8[s][co][k] i8 (5 digits), k=(kh*3+kw)*1024+ci  (R9-proven)
__global__ void slice_w_kernel(const float* __restrict__ W, const int* __restrict__ flags,
                               signed char* __restrict__ ws8) {
    if (flags[0] != 1) return;
    const int EB = flags[2];
    long long gid = blockIdx.x * 256ll + threadIdx.x;
    if (gid >= (long long)CMID * K_TOT) return;
    int co = (int)(gid / K_TOT);
    int k = (int)(gid - (long long)co * K_TOT);
    int pl = k >> 10, ci = k & 1023;
    double u = ldexp((double)W[((size_t)co * CIN + ci) * 9 + pl], -EB);
#pragma unroll
    for (int s = 0; s < 5; ++s) {
        u *= 128.0; double d = rint(u); u -= d;
        ws8[(size_t)s * (512ll * K_TOT) + (size_t)co * K_TOT + k] = (signed char)(int)d;
    }
}

// ---------------------------------------------------------------------------
// i8-Ozaki conv, TWO batches/launch, 2-kc PHASES (72 phases, 1 barrier each).
// Per phase: prefetch A(kc0)+A(kc1) + issue B-global(next phase), then 160
// MFMAs on LDS-staged B, then LDS write + barrier. Buffer parity: phase p
// reads buf[p&1], writes buf[(p+1)&1] (race-free with 1 barrier/phase).
// Fragment/staging byte-mapping identical to the R12-proven kernel.
// ---------------------------------------------------------------------------
__global__ __launch_bounds__(256, 2) void conv3x3_i8d(
    const signed char* __restrict__ xs, const signed char* __restrict__ ws8,
    const float* __restrict__ bconv, const int* __restrict__ flags,
    const int* __restrict__ itab, double* __restrict__ featB2) {
    if (flags[0] != 1) return;
    const int EA = flags[1], EB = flags[2];
    __shared__ signed char Bsm[2 * 2 * 12800];   // [buf][kcsub][5s][32col][80B]
    const int tid = threadIdx.x;
    const int l = tid & 63, w = tid >> 6;
    const int n0 = blockIdx.x * 32;
    const int mbase = blockIdx.y * 128 + w * 32;
    const int z = blockIdx.z;
    const signed char* xsb = xs + (size_t)z * XS_BATCH;

    const int rA = itab[l];
    const int gA = itab[64 + l];
    const int gB = itab[128 + l];
    const int cB = itab[192 + l];
    int dR[4], dC[4];
#pragma unroll
    for (int r = 0; r < 4; ++r) { dR[r] = itab[256 + l * 4 + r]; dC[r] = itab[512 + l * 4 + r]; }

    int yyr[2], xxr[2]; bool vmr[2];
#pragma unroll
    for (int rt = 0; rt < 2; ++rt) {
        int m = mbase + rt * 16 + rA;
        vmr[rt] = (m < NPIX);
        int mm = vmr[rt] ? m : 0;
        yyr[rt] = mm / FWW;
        xxr[rt] = mm - yyr[rt] * FWW;
    }

    // B stage roles (constant per thread): 640 16B-vectors per kc
    const int u0 = tid, u1 = tid + 256, u2 = tid + 512;
    const int s0 = u0 >> 7, c0 = (u0 & 127) >> 2, g0 = u0 & 3;
    const int s1 = u1 >> 7, c1 = (u1 & 127) >> 2, g1 = u1 & 3;
    const int s2 = u2 >> 7, c2 = (u2 & 127) >> 2, g2 = u2 & 3;
    const bool do2 = (u2 < 640);
    const signed char* gp0 = ws8 + ((size_t)(s0 * 512 + n0 + c0)) * K_TOT + g0 * 16;
    const signed char* gp1 = ws8 + ((size_t)(s1 * 512 + n0 + c1)) * K_TOT + g1 * 16;
    const signed char* gp2 = ws8 + ((size_t)(s2 * 512 + n0 + c2)) * K_TOT + g2 * 16;
    const int ld0 = s0 * 2560 + c0 * 80 + g0 * 16;
    const int ld1 = s1 * 2560 + c1 * 80 + g1 * 16;
    const int ld2 = s2 * 2560 + c2 * 80 + g2 * 16;
    const int fb0 = cB * 80 + gB * 16;
    const int fb1 = (16 + cB) * 80 + gB * 16;

    i32x4 acc[6][2][2];
#pragma unroll
    for (int s = 0; s < 6; ++s)
#pragma unroll
        for (int rt = 0; rt < 2; ++rt)
#pragma unroll
            for (int ct = 0; ct < 2; ++ct) acc[s][rt][ct] = (i32x4){0, 0, 0, 0};

#define KOFS(KC) ((size_t)((KC) >> 4) * 1024 + (size_t)(((KC) & 15) << 6))

#define LOAD_A(KC, AF) do {                                                   \
        const int pl_ = (KC) >> 4;                                            \
        const int kh_ = pl_ / 3, kw_ = pl_ - kh_ * 3;                         \
        const int c16_ = (((KC) & 15) << 2) + gA;                             \
        _Pragma("unroll")                                                     \
        for (int rt = 0; rt < 2; ++rt) {                                      \
            const int iy_ = yyr[rt] + kh_ - 1, ix_ = xxr[rt] + kw_ - 1;       \
            const bool ok_ = vmr[rt] && iy_ >= 0 && iy_ < FHH && ix_ >= 0 && ix_ < FWW; \
            const int pix_ = ok_ ? (iy_ * FWW + ix_) : 0;                     \
            const signed char* ap_ = xsb + ((size_t)(c16_ * NPIX + pix_) * 6) * 16; \
            _Pragma("unroll")                                                 \
            for (int s = 0; s < 6; ++s) {                                     \
                i32x4 v_ = *(const i32x4*)(ap_ + s * 16);                     \
                if (!ok_) v_ = (i32x4){0, 0, 0, 0};                           \
                AF[s][rt] = v_;                                               \
            }                                                                 \
        }                                                                     \
    } while (0)

#define MFMA_KC(BB, AF) do {                                                  \
        _Pragma("unroll")                                                     \
        for (int j = 0; j < 5; ++j) {                                         \
            i32x4 bf0 = *(const i32x4*)((BB) + j * 2560 + fb0);               \
            i32x4 bf1 = *(const i32x4*)((BB) + j * 2560 + fb1);               \
            _Pragma("unroll")                                                 \
            for (int i = 0; i + j <= 5; ++i) {                                \
                acc[i + j][0][0] = __builtin_amdgcn_mfma_i32_16x16x64_i8(AF[i][0], bf0, acc[i + j][0][0], 0, 0, 0); \
                acc[i + j][0][1] = __builtin_amdgcn_mfma_i32_16x16x64_i8(AF[i][0], bf1, acc[i + j][0][1], 0, 0, 0); \
                acc[i + j][1][0] = __builtin_amdgcn_mfma_i32_16x16x64_i8(AF[i][1], bf0, acc[i + j][1][0], 0, 0, 0); \
                acc[i + j][1][1] = __builtin_amdgcn_mfma_i32_16x16x64_i8(AF[i][1], bf1, acc[i + j][1][1], 0, 0, 0); \
            }                                                                 \
        }                                                                     \
    } while (0)

    {   // prologue: stage phase 0 (kc 0,1) into buf 0
        size_t k0 = KOFS(0), k1 = KOFS(1);
        *(i32x4*)&Bsm[ld0] = *(const i32x4*)(gp0 + k0);
        *(i32x4*)&Bsm[ld1] = *(const i32x4*)(gp1 + k0);
        if (do2) *(i32x4*)&Bsm[ld2] = *(const i32x4*)(gp2 + k0);
        *(i32x4*)&Bsm[12800 + ld0] = *(const i32x4*)(gp0 + k1);
        *(i32x4*)&Bsm[12800 + ld1] = *(const i32x4*)(gp1 + k1);
        if (do2) *(i32x4*)&Bsm[12800 + ld2] = *(const i32x4*)(gp2 + k1);
    }
    __syncthreads();

    for (int ph = 0; ph < 72; ++ph) {
        const int cur = ph & 1;
        const int kc0 = ph * 2, kc1 = ph * 2 + 1;
        // prefetch A for both kc of this phase
        i32x4 af0[6][2], af1[6][2];
        LOAD_A(kc0, af0);
        LOAD_A(kc1, af1);
        // issue B-global loads for next phase
        i32x4 sva0, sva1, sva2, svb0, svb1, svb2;
        if (ph + 1 < 72) {
            size_t ka = KOFS(kc0 + 2), kb = KOFS(kc1 + 2);
            sva0 = *(const i32x4*)(gp0 + ka);
            sva1 = *(const i32x4*)(gp1 + ka);
            if (do2) sva2 = *(const i32x4*)(gp2 + ka);
            svb0 = *(const i32x4*)(gp0 + kb);
            svb1 = *(const i32x4*)(gp1 + kb);
            if (do2) svb2 = *(const i32x4*)(gp2 + kb);
        }
        // 160 MFMAs on current buffers
        const signed char* bb0 = &Bsm[cur * 25600];
        const signed char* bb1 = &Bsm[cur * 25600 + 12800];
        MFMA_KC(bb0, af0);
        MFMA_KC(bb1, af1);
        // write next phase's B to other buffer; one barrier per phase
        if (ph + 1 < 72) {
            signed char* bw = &Bsm[(cur ^ 1) * 25600];
            *(i32x4*)&bw[ld0] = sva0;
            *(i32x4*)&bw[ld1] = sva1;
            if (do2) *(i32x4*)&bw[ld2] = sva2;
            *(i32x4*)&bw[12800 + ld0] = svb0;
            *(i32x4*)&bw[12800 + ld1] = svb1;
            if (do2) *(i32x4*)&bw[12800 + ld2] = svb2;
        }
        __syncthreads();
    }
#undef KOFS
#undef LOAD_A
#undef MFMA_KC

    double sc[6];
#pragma unroll
    for (int s = 0; s < 6; ++s) sc[s] = ldexp(1.0, EA + EB - 7 * (s + 2));
#pragma unroll
    for (int rt = 0; rt < 2; ++rt)
#pragma unroll
        for (int ct = 0; ct < 2; ++ct)
#pragma unroll
            for (int r = 0; r < 4; ++r) {
                int grow = mbase + rt * 16 + dR[r];
                int gcol = n0 + ct * 16 + dC[r];
                if (grow < NPIX) {
                    double v = (double)bconv[gcol];
#pragma unroll
                    for (int s = 0; s < 6; ++s) v += sc[s] * (double)acc[s][rt][ct][r];
                    featB2[((size_t)(z * NPIX + grow)) * CMID + gcol] = fmax(v, 0.0);
                }
            }
}

// K0: W_conv -> Wt[k][co] fp32 (fallback)
__global__ void wt3x3_kernel(const float* __restrict__ W, float* __restrict__ Wt) {
    int gid = blockIdx.x * 256 + threadIdx.x;
    if (gid >= K_TOT * CMID) return;
    int co = gid & 511;
    int k  = gid >> 9;
    int pl = k >> 10;
    int ci = k & 1023;
    Wt[gid] = W[((size_t)co * CIN + ci) * 9 + pl];
}

__global__ void wt1x1_kernel(const float* __restrict__ Wc, const float* __restrict__ Wb,
                             double* __restrict__ Wt2pD) {
    int gid = blockIdx.x * 256 + threadIdx.x;
    if (gid >= CMID * 64) return;
    int n = gid & 63, k = gid >> 6;
    double v = 0.0;
    if (n < 18)      v = (double)Wc[(size_t)n * CMID + k];
    else if (n < 54) v = (double)Wb[(size_t)(n - 18) * CMID + k];
    Wt2pD[gid] = v;
}

// Fallback f64 MFMA conv (R6-verified), runs only when flags[0]==0
#define ASZ (32 * 72)
__global__ __launch_bounds__(256, 4) void conv3x3_mfma(
    const float* __restrict__ x, const float* __restrict__ Wt,
    const float* __restrict__ bconv, const int* __restrict__ tab,
    const int* __restrict__ flags, double* __restrict__ feat) {
    if (flags[0] == 1) return;
    __shared__ float As[2 * ASZ];
    __shared__ float Bs[2 * ASZ];
    const int tid = threadIdx.x;
    const int lane = tid & 63;
    const int wave = tid >> 6;
    const int wm = wave >> 1;
    const int wn = wave & 1;
    const int n0 = blockIdx.x * 64;
    const int m0 = blockIdx.y * 64;

    const int aRow = tab[lane];
    const int aK   = tab[64 + lane];
    const int bK   = tab[128 + lane];
    const int bCol = tab[192 + lane];
    int dRow[4], dCol[4];
#pragma unroll
    for (int r = 0; r < 4; ++r) {
        dRow[r] = tab[256 + lane * 4 + r];
        dCol[r] = tab[512 + lane * 4 + r];
    }
    const int mm = tid & 63;
    const int t6 = tid >> 6;
    const int m = m0 + mm;
    const bool vm = (m < M_TOT);
    int b = 0, yy = 0, xx = 0;
    if (vm) { b = m / NPIX; int r = m - b * NPIX; yy = r / FWW; xx = r - yy * FWW; }
    const int bk2 = tid >> 4;
    const int bn2 = (tid & 15) << 2;

    f64x4 acc[2][2];
#pragma unroll
    for (int i = 0; i < 2; ++i)
#pragma unroll
        for (int j = 0; j < 2; ++j) acc[i][j] = (f64x4){0.0, 0.0, 0.0, 0.0};

    const float* aBase = &As[aK * 72 + wm * 32 + aRow];
    const float* bBase = &Bs[bK * 72 + wn * 32 + bCol];

#define STAGE_REGS(KC, VA, VB0, VB1) do {                                     \
        const int pl_ = (KC) >> 5;                                            \
        const int kh_ = pl_ / 3, kw_ = pl_ - kh_ * 3;                         \
        const int ci0_ = ((KC) & 31) << 5;                                    \
        const int iy_ = yy + kh_ - 1, ix_ = xx + kw_ - 1;                     \
        const bool ok_ = vm && (iy_ >= 0) && (iy_ < FHH) && (ix_ >= 0) && (ix_ < FWW); \
        const float* ap_ = x + ((size_t)(b * CIN + ci0_ + t6)) * NPIX + iy_ * FWW + ix_; \
        _Pragma("unroll")                                                     \
        for (int r = 0; r < 8; ++r) {                                         \
            float v_ = 0.f;                                                   \
            if (ok_) v_ = ap_[(size_t)r * 4 * NPIX];                          \
            VA[r] = v_;                                                       \
        }                                                                     \
        const float4* wp_ = (const float4*)(Wt + (size_t)(((KC) << 5) + bk2) * CMID + n0 + bn2); \
        VB0 = wp_[0];                                                         \
        VB1 = wp_[2048];                                                      \
    } while (0)

#define WRITE_TILE(BUF, VA, VB0, VB1) do {                                    \
        _Pragma("unroll")                                                     \
        for (int r = 0; r < 8; ++r)                                           \
            As[(BUF) * ASZ + (t6 + r * 4) * 72 + mm] = VA[r];                 \
        *(float4*)&Bs[(BUF) * ASZ + bk2 * 72 + bn2] = VB0;                    \
        *(float4*)&Bs[(BUF) * ASZ + (bk2 + 16) * 72 + bn2] = VB1;             \
    } while (0)

#define MFMA_PHASE(BUF) do {                                                  \
        _Pragma("unroll")                                                     \
        for (int ks = 0; ks < 8; ++ks) {                                      \
            double a0 = (double)aBase[(BUF) * ASZ + ks * 288];                \
            double a1 = (double)aBase[(BUF) * ASZ + ks * 288 + 16];           \
            double b0 = (double)bBase[(BUF) * ASZ + ks * 288];                \
            double b1 = (double)bBase[(BUF) * ASZ + ks * 288 + 16];           \
            acc[0][0] = __builtin_amdgcn_mfma_f64_16x16x4f64(a0, b0, acc[0][0], 0, 0, 0); \
            acc[0][1] = __builtin_amdgcn_mfma_f64_16x16x4f64(a0, b1, acc[0][1], 0, 0, 0); \
            acc[1][0] = __builtin_amdgcn_mfma_f64_16x16x4f64(a1, b0, acc[1][0], 0, 0, 0); \
            acc[1][1] = __builtin_amdgcn_mfma_f64_16x16x4f64(a1, b1, acc[1][1], 0, 0, 0); \
        }                                                                     \
    } while (0)

    float va[8]; float4 vb0, vb1;
    float wa[8]; float4 wb0, wb1;
    STAGE_REGS(0, va, vb0, vb1);
    WRITE_TILE(0, va, vb0, vb1);
    __syncthreads();
    for (int kc = 0; kc < 288; kc += 2) {
        STAGE_REGS(kc + 1, wa, wb0, wb1);
        MFMA_PHASE(0);
        WRITE_TILE(1, wa, wb0, wb1);
        __syncthreads();
        if (kc + 2 < 288) {
            STAGE_REGS(kc + 2, va, vb0, vb1);
            MFMA_PHASE(1);
            WRITE_TILE(0, va, vb0, vb1);
            __syncthreads();
        } else {
            MFMA_PHASE(1);
        }
    }
#undef STAGE_REGS
#undef WRITE_TILE
#undef MFMA_PHASE
#pragma unroll
    for (int mi = 0; mi < 2; ++mi)
#pragma unroll
        for (int nj = 0; nj < 2; ++nj)
#pragma unroll
            for (int r = 0; r < 4; ++r) {
                int mg  = m0 + wm * 32 + mi * 16 + dRow[r];
                int col = n0 + wn * 32 + nj * 16 + dCol[r];
                if (mg < M_TOT)
                    feat[(size_t)mg * CMID + col] =
                        fmax(acc[mi][nj][r] + (double)bconv[col], 0.0);
            }
}

// K2a: 1x1 convs for ONE batch pair (i8 mode). featB2 = 4788 rows.
__global__ __launch_bounds__(256) void conv1x1_i8(
    const double* __restrict__ featB2, const double* __restrict__ Wt2pD,
    const float* __restrict__ bcls, const float* __restrict__ bbx,
    const int* __restrict__ flags, int pair, double* __restrict__ out54) {
    if (flags[0] != 1) return;
    __shared__ double As[4 * 512];
    __shared__ double Bsh[64 * 64];
    int tid = threadIdx.x;
    int m0 = blockIdx.x * 4;                   // local row in [0, 4788)
    for (int off = tid; off < 2048; off += 256) As[off] = featB2[(size_t)m0 * CMID + off];
    int p = tid >> 6, n = tid & 63;
    double acc = 0.0;
    for (int c = 0; c < 8; ++c) {
        __syncthreads();
        for (int off = tid; off < 4096; off += 256) Bsh[off] = Wt2pD[c * 4096 + off];
        __syncthreads();
        const double* ap = &As[p * 512 + c * 64];
#pragma unroll 8
        for (int k2 = 0; k2 < 64; ++k2) acc = fma(ap[k2], Bsh[k2 * 64 + n], acc);
    }
    if (n < 54) {
        double bias = (double)((n < 18) ? bcls[n] : bbx[n - 18]);
        out54[((size_t)(pair * 4788 + m0 + p)) * 64 + n] = acc + bias;
    }
}

// K2b: 1x1 convs, fallback mode (full featD)
__global__ __launch_bounds__(256) void conv1x1_fb(
    const double* __restrict__ feat, const double* __restrict__ Wt2pD,
    const float* __restrict__ bcls, const float* __restrict__ bbx,
    const int* __restrict__ flags, double* __restrict__ out54) {
    if (flags[0] == 1) return;
    __shared__ double As[4 * 512];
    __shared__ double Bsh[64 * 64];
    int tid = threadIdx.x;
    int m0 = blockIdx.x * 4;
    for (int off = tid; off < 2048; off += 256) As[off] = feat[(size_t)m0 * CMID + off];
    int p = tid >> 6, n = tid & 63;
    double acc = 0.0;
    for (int c = 0; c < 8; ++c) {
        __syncthreads();
        for (int off = tid; off < 4096; off += 256) Bsh[off] = Wt2pD[c * 4096 + off];
        __syncthreads();
        const double* ap = &As[p * 512 + c * 64];
#pragma unroll 8
        for (int k2 = 0; k2 < 64; ++k2) acc = fma(ap[k2], Bsh[k2 * 64 + n], acc);
    }
    if (n < 54) {
        double bias = (double)((n < 18) ? bcls[n] : bbx[n - 18]);
        out54[(size_t)(m0 + p) * 64 + n] = acc + bias;
    }
}

// K2c: softmax-pair + bbox decode + clip, fp64
__global__ void proposals_kernel(const double* __restrict__ out54, const float* __restrict__ iminfo,
                                 double* __restrict__ scoresD, double* __restrict__ propsD) {
    int gid = blockIdx.x * 256 + threadIdx.x;
    if (gid >= BATCH * NSC) return;
    int b = gid / NSC;
    int rem = gid - b * NSC;
    int p = rem / 9;
    int a = rem - p * 9;
    int y = p / FWW, x = p - y * FWW;
    int m = b * NPIX + p;
    const double* row = out54 + (size_t)m * 64;
    double s0 = row[a], s1 = row[9 + a];
    double mx = fmax(s0, s1);
    double e0 = exp(s0 - mx), e1 = exp(s1 - mx);
    scoresD[gid] = e1 / (e0 + e1);
    double dx = row[18 + 4 * a], dy = row[19 + 4 * a], dw = row[20 + 4 * a], dh = row[21 + 4 * a];
    double ax1 = x * 16.0 + ANCX1[a], ay1 = y * 16.0 + ANCY1[a];
    double ax2 = x * 16.0 + ANCX2[a], ay2 = y * 16.0 + ANCY2[a];
    double w = ax2 - ax1 + 1.0, h = ay2 - ay1 + 1.0;
    double cx = ax1 + 0.5 * w, cy = ay1 + 0.5 * h;
    double px = dx * w + cx, py = dy * h + cy;
    double pw = exp(dw) * w, ph = exp(dh) * h;
    double imh = (double)iminfo[b * 3 + 0], imw = (double)iminfo[b * 3 + 1];
    double x1 = fmin(fmax(px - 0.5 * pw, 0.0), imw - 1.0);
    double y1 = fmin(fmax(py - 0.5 * ph, 0.0), imh - 1.0);
    double x2 = fmin(fmax(px + 0.5 * pw, 0.0), imw - 1.0);
    double y2 = fmin(fmax(py + 0.5 * ph, 0.0), imh - 1.0);
    double* o = propsD + (size_t)gid * 4;
    o[0] = x1; o[1] = y1; o[2] = x2; o[3] = y2;
}

// K3: exact top-2000 radix-select + bitonic
__global__ __launch_bounds__(256) void select_kernel(const double* __restrict__ scoresD,
                                                     const double* __restrict__ propsD,
                                                     double* __restrict__ boxesD) {
    __shared__ unsigned int hist4[4][256];
    __shared__ unsigned int histf[256];
    __shared__ unsigned long long keys[2048];
    __shared__ unsigned long long sh_thr;
    __shared__ int sh_need;
    __shared__ int cnt;
    const int b = blockIdx.x, tid = threadIdx.x;
    const int w4 = tid >> 6;
    const double* sc = scoresD + (size_t)b * NSC;

    unsigned long long prefix = 0ull;
    int need = PRE_N;
    for (int d = 7; d >= 0; --d) {
        for (int z = tid; z < 1024; z += 256) ((unsigned int*)hist4)[z] = 0u;
        __syncthreads();
        const int shift = d * 8;
        const unsigned long long maskAbove = (d == 7) ? 0ull : (~0ull << (shift + 8));
        for (int i = tid; i < NSC; i += 256) {
            unsigned long long sb = (unsigned long long)__double_as_longlong(sc[i]);
            unsigned long long key = (sb & ~0x7FFFull) | (unsigned long long)((~i) & 0x7FFF);
            if (((key ^ prefix) & maskAbove) == 0ull)
                atomicAdd(&hist4[w4][(unsigned int)(key >> shift) & 255u], 1u);
        }
        __syncthreads();
        histf[tid] = hist4[0][tid] + hist4[1][tid] + hist4[2][tid] + hist4[3][tid];
        __syncthreads();
        if (tid == 0) {
            int acc = 0, v = 255;
            for (; v > 0; --v) {
                int c = (int)histf[v];
                if (acc + c >= need) break;
                acc += c;
            }
            sh_thr = prefix | ((unsigned long long)(unsigned int)v << shift);
            sh_need = need - acc;
        }
        __syncthreads();
        prefix = sh_thr;
        need = sh_need;
        __syncthreads();
    }
    if (tid == 0) cnt = 0;
    __syncthreads();
    for (int i = tid; i < NSC; i += 256) {
        unsigned long long sb = (unsigned long long)__double_as_longlong(sc[i]);
        unsigned long long key = (sb & ~0x7FFFull) | (unsigned long long)((~i) & 0x7FFF);
        if (key >= prefix) {
            int slot = atomicAdd(&cnt, 1);
            if (slot < 2048) keys[slot] = key;
        }
    }
    __syncthreads();
    int c0 = cnt;
    for (int i = tid; i < 2048; i += 256)
        if (i >= c0) keys[i] = 0ull;
    for (int k2 = 2; k2 <= 2048; k2 <<= 1)
        for (int j = k2 >> 1; j > 0; j >>= 1) {
            __syncthreads();
            for (int i = tid; i < 2048; i += 256) {
                int l = i ^ j;
                if (l > i) {
                    unsigned long long a = keys[i], c = keys[l];
                    bool up = (i & k2) == 0;
                    if (up ? (a < c) : (a > c)) { keys[i] = c; keys[l] = a; }
                }
            }
        }
    __syncthreads();
    const double* pr = propsD + (size_t)b * NSC * 4;
    double* bs = boxesD + (size_t)b * PRE_N * 4;
    for (int r = tid; r < PRE_N; r += 256) {
        int idx = (int)((~keys[r]) & 0x7FFF);
        if (idx >= NSC) idx = 0;
        bs[r * 4 + 0] = pr[(size_t)idx * 4 + 0];
        bs[r * 4 + 1] = pr[(size_t)idx * 4 + 1];
        bs[r * 4 + 2] = pr[(size_t)idx * 4 + 2];
        bs[r * 4 + 3] = pr[(size_t)idx * 4 + 3];
    }
}

// K4a: fp64 IoU suppression bitmask
__global__ __launch_bounds__(256) void iou_mask_kernel(const double* __restrict__ boxesD,
                                                       unsigned long long* __restrict__ supmask) {
    __shared__ double bx[PRE_N * 4];
    int b = blockIdx.x;
    int i0 = blockIdx.y * 80;
    const double* src = boxesD + (size_t)b * PRE_N * 4;
    for (int o = threadIdx.x; o < PRE_N * 4; o += 256) bx[o] = src[o];
    __syncthreads();
    int ty = threadIdx.x >> 5, jw = threadIdx.x & 31;
    for (int ii = ty; ii < 80; ii += 8) {
        int i = i0 + ii;
        double bix1 = bx[i * 4 + 0], biy1 = bx[i * 4 + 1], bix2 = bx[i * 4 + 2], biy2 = bx[i * 4 + 3];
        double areai = (bix2 - bix1 + 1.0) * (biy2 - biy1 + 1.0);
        unsigned long long bits = 0ull;
        for (int t = 0; t < 64; ++t) {
            int j = t * 32 + jw;
            if (j > i && j < PRE_N) {
                double bjx1 = bx[j * 4 + 0], bjy1 = bx[j * 4 + 1], bjx2 = bx[j * 4 + 2], bjy2 = bx[j * 4 + 3];
                double iw = fmin(bix2, bjx2) - fmax(bix1, bjx1) + 1.0; iw = fmax(iw, 0.0);
                double ih = fmin(biy2, bjy2) - fmax(biy1, bjy1) + 1.0; ih = fmax(ih, 0.0);
                double inter = iw * ih;
                double areaj = (bjx2 - bjx1 + 1.0) * (bjy2 - bjy1 + 1.0);
                double iou = inter / (areai + areaj - inter);
                if (iou > 0.7) bits |= (1ull << t);
            }
        }
        supmask[((size_t)b * PRE_N + i) * 32 + jw] = bits;
    }
}

// K4b: greedy suppression + first-300 + fp32 output
__global__ void nms_final_kernel(const unsigned long long* __restrict__ supmask,
                                 const double* __restrict__ boxesD,
                                 float* __restrict__ out) {
    int b = blockIdx.x;
    int lane = threadIdx.x;
    int w = lane & 31;
    const unsigned long long* mask = supmask + (size_t)b * PRE_N * 32;
    int nbits = (w < 16) ? 63 : 62;
    unsigned long long kw = (1ull << nbits) - 1ull;
    unsigned long long rr[16];
#pragma unroll
    for (int d2 = 0; d2 < 16; ++d2) rr[d2] = mask[d2 * 32 + w];
    for (int i = 0; i < PRE_N; i += 16) {
#pragma unroll
        for (int u2 = 0; u2 < 16; ++u2) {
            int ii = i + u2;
            unsigned long long rcur = rr[u2];
            int ip = ii + 16;
            rr[u2] = (ip < PRE_N) ? mask[ip * 32 + w] : 0ull;
            unsigned long long kword = __shfl(kw, ii & 31);
            if ((kword >> (ii >> 5)) & 1ull) kw &= ~rcur;
        }
    }
    __shared__ unsigned long long keepw[32];
    __shared__ int pos[POST_N];
    if (lane < 32) keepw[lane] = kw;
    __syncthreads();
    if (lane == 0) {
        int c2 = 0;
        for (int j = 0; j < PRE_N && c2 < POST_N; ++j)
            if ((keepw[j & 31] >> (j >> 5)) & 1ull) pos[c2++] = j;
        for (int j = 0; j < PRE_N && c2 < POST_N; ++j)
            if (!((keepw[j & 31] >> (j >> 5)) & 1ull)) pos[c2++] = j;
    }
    __syncthreads();
    for (int r = lane; r < POST_N; r += 64) {
        int p = pos[r];
        const double* bxp = boxesD + ((size_t)b * PRE_N + p) * 4;
        float* o = out + ((size_t)b * POST_N + r) * 5;
        o[0] = (float)b; o[1] = (float)bxp[0]; o[2] = (float)bxp[1];
        o[3] = (float)bxp[2]; o[4] = (float)bxp[3];
    }
    if (b == 0 && lane == 0) { out[BATCH * POST_N * 5] = 0.f; out[BATCH * POST_N * 5 + 1] = 0.f; }
}

extern "C" void kernel_launch(void* const* d_in, const int* in_sizes, int n_in,
                              void* d_out, int out_size, void* d_ws, size_t ws_size,
                              hipStream_t stream) {
    (void)in_sizes; (void)n_in; (void)out_size;
    const float* base_feat = (const float*)d_in[0];
    const float* im_info   = (const float*)d_in[1];
    const float* W_conv    = (const float*)d_in[4];
    const float* b_conv    = (const float*)d_in[5];
    const float* W_cls     = (const float*)d_in[6];
    const float* b_cls     = (const float*)d_in[7];
    const float* W_bbox    = (const float*)d_in[8];
    const float* b_bbox    = (const float*)d_in[9];
    float* out = (float*)d_out;

    // Layout (total 118,740,096 B == R9-R12-proven gate).
    char* W = (char*)d_ws;
    signed char* xsA = (signed char*)W;                   // 14,708,736
    double* featB2   = (double*)(W + 29417472);           // 19,611,648 (pair buffer)
    double* featD    = (double*)W;                        // fallback full
    float*  Wt       = (float*)(W + 78446592);            // 18,874,368 (fallback)
    signed char* ws8 = (signed char*)(W + 78446592);      // 23,592,960 (i8, clobbers Wt)
    double* out54D   = (double*)(W + 102039552);          // 9,805,824
    double* scoresD  = (double*)(W + 111845376);          // 1,378,944
    double* propsD   = (double*)(W + 113224320);          // 5,515,776 -> 118,740,096
    double* Wt2pD    = (double*)(W + 113224320);          // props-head tails (disjoint lifetime)
    int*    tab      = (int*)(W + 113486464);
    int*    itab     = (int*)(W + 113489536);
    int*    iflags   = (int*)(W + 113492608);
    unsigned long long* supmask = (unsigned long long*)W; // R0 dead after conv1x1
    double* boxesD   = scoresD;                           // written at end of select

    bool i8cap = (ws_size >= 118740096ull);

    flaginit_kernel<<<1, 64, 0, stream>>>(iflags);
    mfma_probe_kernel<<<1, 64, 0, stream>>>(tab);
    if (i8cap) {
        i8_probe_kernel<<<1, 64, 0, stream>>>(itab, iflags);
        maxabs_kernel<<<1024, 256, 0, stream>>>(base_feat, (long long)BATCH * CIN * NPIX,
                                                (unsigned*)&iflags[3]);
        maxabs_kernel<<<128, 256, 0, stream>>>(W_conv, (long long)CMID * CIN * 9,
                                               (unsigned*)&iflags[4]);
        prep_kernel<<<1, 64, 0, stream>>>(iflags);
    }
    wt3x3_kernel<<<(K_TOT * CMID + 255) / 256, 256, 0, stream>>>(W_conv, Wt);
    wt1x1_kernel<<<(CMID * 64 + 255) / 256, 256, 0, stream>>>(W_cls, W_bbox, Wt2pD);
    if (i8cap) {
        slice_w_kernel<<<(int)((4718592 + 255) / 256), 256, 0, stream>>>(W_conv, iflags, ws8);
        for (int pair = 0; pair < 4; ++pair) {
            slice_x_kernel<<<dim3(10, 64), 256, 0, stream>>>(base_feat, iflags, pair * 2, xsA);
            slice_x_kernel<<<dim3(10, 64), 256, 0, stream>>>(base_feat, iflags, pair * 2 + 1,
                                                             xsA + XS_BATCH);
            conv3x3_i8d<<<dim3(16, 19, 2), 256, 0, stream>>>(xsA, ws8, b_conv, iflags, itab,
                                                             featB2);
            conv1x1_i8<<<1197, 256, 0, stream>>>(featB2, Wt2pD, b_cls, b_bbox, iflags, pair,
                                                 out54D);
        }
    }
    conv3x3_mfma<<<dim3(8, 300), 256, 0, stream>>>(base_feat, Wt, b_conv, tab, iflags, featD);
    conv1x1_fb<<<M_TOT / 4, 256, 0, stream>>>(featD, Wt2pD, b_cls, b_bbox, iflags, out54D);
    proposals_kernel<<<(BATCH * NSC + 255) / 256, 256, 0, stream>>>(out54D, im_info, scoresD, propsD);
    select_kernel<<<BATCH, 256, 0, stream>>>(scoresD, propsD, boxesD);
    iou_mask_kernel<<<dim3(BATCH, 25), 256, 0, stream>>>(boxesD, supmask);
    nms_final_kernel<<<BATCH, 64, 0, stream>>>(supmask, boxesD, out);
}

// Round 14
// 3174.028 us; speedup vs baseline: 1.7941x; 1.0268x over previous
//
#include <hip/hip_runtime.h>

#define FHH 38
#define FWW 63
#define NPIX 2394        // 38*63
#define BATCH 8
#define CIN 1024
#define CMID 512
#define NSC 21546        // NPIX*9
#define M_TOT 19152      // BATCH*NPIX
#define K_TOT 9216       // CIN*9
#define PRE_N 2000
#define POST_N 300
#define XS_BATCH 14708736ll      // 64 c16 * 2394 pix * 96 B

typedef double f64x4 __attribute__((ext_vector_type(4)));
typedef int    i32x4 __attribute__((ext_vector_type(4)));

// exact anchors
__device__ const double ANCX1[9] = {-84.,-176.,-360.,-56.,-120.,-248.,-36.,-80.,-168.};
__device__ const double ANCY1[9] = {-40.,-88.,-184.,-56.,-120.,-248.,-80.,-168.,-344.};
__device__ const double ANCX2[9] = {99.,191.,375.,71.,135.,263.,51.,95.,183.};
__device__ const double ANCY2[9] = {55.,103.,199.,71.,135.,263.,95.,183.,359.};

__device__ __forceinline__ int h1f(int l, int t) { return ((l * 16 + t) * 37) % 61 - 30; }
__device__ __forceinline__ int h2f(int l, int t) { return ((l * 16 + t) * 53) % 59 - 29; }

// ---------------------------------------------------------------------------
// f64 MFMA layout probe (R4-verified; feeds the fallback conv)
// ---------------------------------------------------------------------------
__global__ void mfma_probe_kernel(int* __restrict__ tab) {
    const int l = threadIdx.x;
    __shared__ int aiS[64], bjS[64], kbS[64];
    const f64x4 zero = {0.0, 0.0, 0.0, 0.0};
    int di[4] = {-1, -1, -1, -1}, dj[4] = {-1, -1, -1, -1};
    int ai_l = 0, bj_l = 0, ka_l = 0;
    kbS[l] = 0x7fffffff;
    __syncthreads();
    const double bval = __longlong_as_double((long long)(1023 + l) << 52);
    for (int p = 0; p < 64; ++p) {
        double a = (l == p) ? 1.0 : 0.0;
        f64x4 d = __builtin_amdgcn_mfma_f64_16x16x4f64(a, bval, zero, 0, 0, 0);
        int lmin = 0x7fffffff, kmin = 0x7fffffff;
        bool lit[4]; int qv[4];
#pragma unroll
        for (int r = 0; r < 4; ++r) {
            lit[r] = (d[r] != 0.0);
            qv[r] = ((__double2hiint(d[r]) >> 20) & 0x7ff) - 1023;
            if (lit[r]) { lmin = min(lmin, di[r] < 0 ? p : di[r]); kmin = min(kmin, qv[r]); }
        }
#pragma unroll
        for (int off = 32; off > 0; off >>= 1) {
            lmin = min(lmin, __shfl_xor(lmin, off));
            kmin = min(kmin, __shfl_xor(kmin, off));
        }
#pragma unroll
        for (int r = 0; r < 4; ++r)
            if (lit[r]) { di[r] = lmin; atomicMin(&kbS[qv[r]], kmin); }
        if (l == p) { ai_l = lmin; ka_l = kmin; }
    }
    for (int q = 0; q < 64; ++q) {
        double b = (l == q) ? 1.0 : 0.0;
        f64x4 d = __builtin_amdgcn_mfma_f64_16x16x4f64(1.0, b, zero, 0, 0, 0);
        int lmin = 0x7fffffff;
        bool lit[4];
#pragma unroll
        for (int r = 0; r < 4; ++r) {
            lit[r] = (d[r] != 0.0);
            if (lit[r]) lmin = min(lmin, dj[r] < 0 ? q : dj[r]);
        }
#pragma unroll
        for (int off = 32; off > 0; off >>= 1) lmin = min(lmin, __shfl_xor(lmin, off));
#pragma unroll
        for (int r = 0; r < 4; ++r) if (lit[r]) dj[r] = lmin;
        if (l == q) bj_l = lmin;
    }
    aiS[l] = ai_l; bjS[l] = bj_l;
    __syncthreads();
    int kb_l = kbS[l];
    int a_row_rk = 0, a_k_rk = 0, b_k_rk = 0, b_col_rk = 0;
    for (int t = 0; t < 64; ++t) {
        a_row_rk += (aiS[t] == t && t < ai_l);
        b_col_rk += (bjS[t] == t && t < bj_l);
        a_k_rk   += (kbS[t] == t && t < ka_l);
        b_k_rk   += (kbS[t] == t && t < kb_l);
    }
    tab[l] = a_row_rk; tab[64 + l] = a_k_rk; tab[128 + l] = b_k_rk; tab[192 + l] = b_col_rk;
#pragma unroll
    for (int r = 0; r < 4; ++r) {
        int dr = 0, dc = 0;
        for (int t = 0; t < 64; ++t) {
            dr += (aiS[t] == t && t < di[r]);
            dc += (bjS[t] == t && t < dj[r]);
        }
        tab[256 + l * 4 + r] = dr;
        tab[512 + l * 4 + r] = dc;
    }
}

__global__ void flaginit_kernel(int* __restrict__ f) {
    if (threadIdx.x == 0) { f[0] = 0; f[1] = 0; f[2] = 0; f[3] = 0; f[4] = 0; }
}

// ---------------------------------------------------------------------------
// i8 MFMA probe + self-validation (R9-R13-verified on HW)
// ---------------------------------------------------------------------------
__global__ void i8_probe_kernel(int* __restrict__ itab, int* __restrict__ flags) {
    const int l = threadIdx.x;
    __shared__ int aiS[64], bjS[64], kbS[64];
    __shared__ int pOf[64], qOf[64];
    const i32x4 zero = {0, 0, 0, 0};
    const i32x4 ones = {0x01010101, 0x01010101, 0x01010101, 0x01010101};
    int di[4] = {-1, -1, -1, -1}, dj[4] = {-1, -1, -1, -1};
    int ai_l = -1, bj_l = -1, ka_l = -1;
    kbS[l] = 0x7fffffff; pOf[l] = 0; qOf[l] = 0;
    __syncthreads();

    for (int p = 0; p < 64; ++p) {
        i32x4 a = (l == p) ? ones : zero;
        i32x4 d = __builtin_amdgcn_mfma_i32_16x16x64_i8(a, ones, zero, 0, 0, 0);
        int lmin = 0x7fffffff;
        bool lit[4];
#pragma unroll
        for (int r = 0; r < 4; ++r) {
            lit[r] = (d[r] != 0);
            if (lit[r]) lmin = min(lmin, di[r] < 0 ? p : di[r]);
        }
#pragma unroll
        for (int off = 32; off > 0; off >>= 1) lmin = min(lmin, __shfl_xor(lmin, off));
#pragma unroll
        for (int r = 0; r < 4; ++r) if (lit[r]) di[r] = lmin;
        if (l == p) ai_l = lmin;
    }
    for (int q = 0; q < 64; ++q) {
        i32x4 b = (l == q) ? ones : zero;
        i32x4 d = __builtin_amdgcn_mfma_i32_16x16x64_i8(ones, b, zero, 0, 0, 0);
        int lmin = 0x7fffffff;
        bool lit[4];
#pragma unroll
        for (int r = 0; r < 4; ++r) {
            lit[r] = (d[r] != 0);
            if (lit[r]) lmin = min(lmin, dj[r] < 0 ? q : dj[r]);
        }
#pragma unroll
        for (int off = 32; off > 0; off >>= 1) lmin = min(lmin, __shfl_xor(lmin, off));
#pragma unroll
        for (int r = 0; r < 4; ++r) if (lit[r]) dj[r] = lmin;
        if (l == q) bj_l = lmin;
    }
    {
        unsigned bw = (unsigned)(l + 1);
        bw |= bw << 8; bw |= bw << 16;
        i32x4 bq = {(int)bw, (int)bw, (int)bw, (int)bw};
        for (int p = 0; p < 64; ++p) {
            i32x4 a = (l == p) ? ones : zero;
            i32x4 d = __builtin_amdgcn_mfma_i32_16x16x64_i8(a, bq, zero, 0, 0, 0);
            int kmin = 0x7fffffff;
            bool lit[4]; int qv[4];
#pragma unroll
            for (int r = 0; r < 4; ++r) {
                lit[r] = (d[r] != 0);
                qv[r] = d[r] / 16 - 1;
                if (lit[r]) kmin = min(kmin, qv[r]);
            }
#pragma unroll
            for (int off = 32; off > 0; off >>= 1) kmin = min(kmin, __shfl_xor(kmin, off));
#pragma unroll
            for (int r = 0; r < 4; ++r)
                if (lit[r] && qv[r] >= 0 && qv[r] < 64) atomicMin(&kbS[qv[r]], kmin);
            if (l == p) ka_l = kmin;
        }
    }
    aiS[l] = ai_l; bjS[l] = bj_l;
    __syncthreads();
    int kb_l = kbS[l];
    int rA = 0, gA = 0, gB = 0, cB = 0;
    for (int t = 0; t < 64; ++t) {
        rA += (aiS[t] == t && t < ai_l);
        cB += (bjS[t] == t && t < bj_l);
        gA += (kbS[t] == t && t < ka_l);
        gB += (kbS[t] == t && t < kb_l);
    }
    itab[l] = rA; itab[64 + l] = gA; itab[128 + l] = gB; itab[192 + l] = cB;
    int dR[4], dC[4];
#pragma unroll
    for (int r = 0; r < 4; ++r) {
        int dr = 0, dc = 0;
        for (int t = 0; t < 64; ++t) {
            dr += (aiS[t] == t && t < di[r]);
            dc += (bjS[t] == t && t < dj[r]);
        }
        dR[r] = dr; dC[r] = dc;
        itab[256 + l * 4 + r] = dr;
        itab[512 + l * 4 + r] = dc;
    }
    __syncthreads();
    bool ok = (rA < 16) && (gA < 4) && (cB < 16) && (gB < 4);
    if (ok) { pOf[rA * 4 + gA] = l; qOf[cB * 4 + gB] = l; }
    __syncthreads();
    unsigned wa[4], wb[4];
#pragma unroll
    for (int dw = 0; dw < 4; ++dw) {
        unsigned a = 0, b = 0;
#pragma unroll
        for (int by = 0; by < 4; ++by) {
            int t = dw * 4 + by;
            a |= ((unsigned)(h1f(l, t) & 0xff)) << (8 * by);
            b |= ((unsigned)(h2f(l, t) & 0xff)) << (8 * by);
        }
        wa[dw] = a; wb[dw] = b;
    }
    i32x4 va = {(int)wa[0], (int)wa[1], (int)wa[2], (int)wa[3]};
    i32x4 vb = {(int)wb[0], (int)wb[1], (int)wb[2], (int)wb[3]};
    i32x4 d = __builtin_amdgcn_mfma_i32_16x16x64_i8(va, vb, zero, 0, 0, 0);
#pragma unroll
    for (int r = 0; r < 4; ++r) {
        if (dR[r] >= 16 || dC[r] >= 16) { ok = false; continue; }
        int ref = 0;
        for (int g = 0; g < 4; ++g) {
            int p = pOf[dR[r] * 4 + g], q = qOf[dC[r] * 4 + g];
            for (int t = 0; t < 16; ++t) ref += h1f(p, t) * h2f(q, t);
        }
        ok = ok && (d[r] == ref);
    }
    unsigned long long mb = __ballot(ok);
    if (l == 0) flags[0] = (mb == ~0ull) ? 1 : 0;
}

__global__ void maxabs_kernel(const float* __restrict__ p, long long n, unsigned* __restrict__ out) {
    unsigned mx = 0u;
    for (long long i = blockIdx.x * 256ll + threadIdx.x; i < n; i += (long long)gridDim.x * 256)
        mx = max(mx, __float_as_uint(p[i]) & 0x7fffffffu);
#pragma unroll
    for (int off = 32; off > 0; off >>= 1)
        mx = max(mx, (unsigned)__shfl_xor((int)mx, off));
    if ((threadIdx.x & 63) == 0) atomicMax(out, mx);
}

__global__ void prep_kernel(int* __restrict__ flags) {
    if (threadIdx.x == 0) {
        unsigned ax = (unsigned)flags[3], aw = (unsigned)flags[4];
        flags[1] = (int)((ax >> 23) & 255u) - 127 + 2;   // EA
        flags[2] = (int)((aw >> 23) & 255u) - 127 + 2;   // EB
    }
}

// slice x (ONE batch) -> xs[c16][pix][6][16] i8 digits (R12/R13-proven)
__global__ __launch_bounds__(256) void slice_x_kernel(
    const float* __restrict__ x, const int* __restrict__ flags,
    int batch, signed char* __restrict__ xs) {
    if (flags[0] != 1) return;
    const int EA = flags[1];
    const float sA = __int_as_float((127 - EA) << 23);   // exact 2^-EA
    const int pix = blockIdx.x * 256 + threadIdx.x;
    const int c16 = blockIdx.y;
    if (pix >= NPIX) return;
    unsigned wds[6][4];
#pragma unroll
    for (int s = 0; s < 6; ++s)
#pragma unroll
        for (int dw = 0; dw < 4; ++dw) wds[s][dw] = 0u;
    const float* ap = x + ((size_t)(batch * CIN + c16 * 16)) * NPIX + pix;
#pragma unroll
    for (int t = 0; t < 16; ++t) {
        float u = ap[(size_t)t * NPIX] * sA;
#pragma unroll
        for (int s = 0; s < 6; ++s) {
            u *= 128.f;
            float dd = rintf(u);
            u -= dd;
            wds[s][t >> 2] |= ((unsigned)((int)dd & 0xff)) << ((t & 3) * 8);
        }
    }
    signed char* dst = xs + ((size_t)(c16 * NPIX + pix) * 6) * 16;
#pragma unroll
    for (int s = 0; s < 6; ++s)
        *(i32x4*)(dst + s * 16) =
            (i32x4){(int)wds[s][0], (int)wds[s][1], (int)wds[s][2], (int)wds[s][3]};
}

// slice W_conv -> ws8[s][co][k] i8 (5 digits), k=(kh*3+kw)*1024+ci  (R9-proven)
__global__ void slice_w_kernel(const float* __restrict__ W, const int* __restrict__ flags,
                               signed char* __restrict__ ws8) {
    if (flags[0] != 1) return;
    const int EB = flags[2];
    long long gid = blockIdx.x * 256ll + threadIdx.x;
    if (gid >= (long long)CMID * K_TOT) return;
    int co = (int)(gid / K_TOT);
    int k = (int)(gid - (long long)co * K_TOT);
    int pl = k >> 10, ci = k & 1023;
    double u = ldexp((double)W[((size_t)co * CIN + ci) * 9 + pl], -EB);
#pragma unroll
    for (int s = 0; s < 5; ++s) {
        u *= 128.0; double d = rint(u); u -= d;
        ws8[(size_t)s * (512ll * K_TOT) + (size_t)co * K_TOT + k] = (signed char)(int)d;
    }
}

// ---------------------------------------------------------------------------
// i8-Ozaki conv, TWO batches/launch, 2-kc phases + A SOFTWARE PIPELINE:
// afX/afY alternate kc-granular A fragment sets; A(kc1) loads issue before
// MFMA(kc0), A(next-phase kc0) before MFMA(kc1) -> A latency hides under
// ~408 cy of MFMA each. B LDS double-buffer unchanged (R13-proven bytes).
// ---------------------------------------------------------------------------
__global__ __launch_bounds__(256, 2) void conv3x3_i8e(
    const signed char* __restrict__ xs, const signed char* __restrict__ ws8,
    const float* __restrict__ bconv, const int* __restrict__ flags,
    const int* __restrict__ itab, double* __restrict__ featB2) {
    if (flags[0] != 1) return;
    const int EA = flags[1], EB = flags[2];
    __shared__ signed char Bsm[2 * 2 * 12800];   // [buf][kcsub][5s][32col][80B]
    const int tid = threadIdx.x;
    const int l = tid & 63, w = tid >> 6;
    const int n0 = blockIdx.x * 32;
    const int mbase = blockIdx.y * 128 + w * 32;
    const int z = blockIdx.z;
    const signed char* xsb = xs + (size_t)z * XS_BATCH;

    const int rA = itab[l];
    const int gA = itab[64 + l];
    const int gB = itab[128 + l];
    const int cB = itab[192 + l];
    int dR[4], dC[4];
#pragma unroll
    for (int r = 0; r < 4; ++r) { dR[r] = itab[256 + l * 4 + r]; dC[r] = itab[512 + l * 4 + r]; }

    int yyr[2], xxr[2]; bool vmr[2];
#pragma unroll
    for (int rt = 0; rt < 2; ++rt) {
        int m = mbase + rt * 16 + rA;
        vmr[rt] = (m < NPIX);
        int mm = vmr[rt] ? m : 0;
        yyr[rt] = mm / FWW;
        xxr[rt] = mm - yyr[rt] * FWW;
    }

    // B stage roles (constant per thread): 640 16B-vectors per kc
    const int u0 = tid, u1 = tid + 256, u2 = tid + 512;
    const int s0 = u0 >> 7, c0 = (u0 & 127) >> 2, g0 = u0 & 3;
    const int s1 = u1 >> 7, c1 = (u1 & 127) >> 2, g1 = u1 & 3;
    const int s2 = u2 >> 7, c2 = (u2 & 127) >> 2, g2 = u2 & 3;
    const bool do2 = (u2 < 640);
    const signed char* gp0 = ws8 + ((size_t)(s0 * 512 + n0 + c0)) * K_TOT + g0 * 16;
    const signed char* gp1 = ws8 + ((size_t)(s1 * 512 + n0 + c1)) * K_TOT + g1 * 16;
    const signed char* gp2 = ws8 + ((size_t)(s2 * 512 + n0 + c2)) * K_TOT + g2 * 16;
    const int ld0 = s0 * 2560 + c0 * 80 + g0 * 16;
    const int ld1 = s1 * 2560 + c1 * 80 + g1 * 16;
    const int ld2 = s2 * 2560 + c2 * 80 + g2 * 16;
    const int fb0 = cB * 80 + gB * 16;
    const int fb1 = (16 + cB) * 80 + gB * 16;

    i32x4 acc[6][2][2];
#pragma unroll
    for (int s = 0; s < 6; ++s)
#pragma unroll
        for (int rt = 0; rt < 2; ++rt)
#pragma unroll
            for (int ct = 0; ct < 2; ++ct) acc[s][rt][ct] = (i32x4){0, 0, 0, 0};

#define KOFS(KC) ((size_t)((KC) >> 4) * 1024 + (size_t)(((KC) & 15) << 6))

#define LOAD_A(KC, AF) do {                                                   \
        const int pl_ = (KC) >> 4;                                            \
        const int kh_ = pl_ / 3, kw_ = pl_ - kh_ * 3;                         \
        const int c16_ = (((KC) & 15) << 2) + gA;                             \
        _Pragma("unroll")                                                     \
        for (int rt = 0; rt < 2; ++rt) {                                      \
            const int iy_ = yyr[rt] + kh_ - 1, ix_ = xxr[rt] + kw_ - 1;       \
            const bool ok_ = vmr[rt] && iy_ >= 0 && iy_ < FHH && ix_ >= 0 && ix_ < FWW; \
            const int pix_ = ok_ ? (iy_ * FWW + ix_) : 0;                     \
            const signed char* ap_ = xsb + ((size_t)(c16_ * NPIX + pix_) * 6) * 16; \
            _Pragma("unroll")                                                 \
            for (int s = 0; s < 6; ++s) {                                     \
                i32x4 v_ = *(const i32x4*)(ap_ + s * 16);                     \
                if (!ok_) v_ = (i32x4){0, 0, 0, 0};                           \
                AF[s][rt] = v_;                                               \
            }                                                                 \
        }                                                                     \
    } while (0)

#define MFMA_KC(BB, AF) do {                                                  \
        _Pragma("unroll")                                                     \
        for (int j = 0; j < 5; ++j) {                                         \
            i32x4 bf0 = *(const i32x4*)((BB) + j * 2560 + fb0);               \
            i32x4 bf1 = *(const i32x4*)((BB) + j * 2560 + fb1);               \
            _Pragma("unroll")                                                 \
            for (int i = 0; i + j <= 5; ++i) {                                \
                acc[i + j][0][0] = __builtin_amdgcn_mfma_i32_16x16x64_i8(AF[i][0], bf0, acc[i + j][0][0], 0, 0, 0); \
                acc[i + j][0][1] = __builtin_amdgcn_mfma_i32_16x16x64_i8(AF[i][0], bf1, acc[i + j][0][1], 0, 0, 0); \
                acc[i + j][1][0] = __builtin_amdgcn_mfma_i32_16x16x64_i8(AF[i][1], bf0, acc[i + j][1][0], 0, 0, 0); \
                acc[i + j][1][1] = __builtin_amdgcn_mfma_i32_16x16x64_i8(AF[i][1], bf1, acc[i + j][1][1], 0, 0, 0); \
            }                                                                 \
        }                                                                     \
    } while (0)

    i32x4 afX[6][2], afY[6][2];
    {   // prologue: stage phase 0 B (kc 0,1) into buf 0; prefetch A(kc0)
        size_t k0 = KOFS(0), k1 = KOFS(1);
        *(i32x4*)&Bsm[ld0] = *(const i32x4*)(gp0 + k0);
        *(i32x4*)&Bsm[ld1] = *(const i32x4*)(gp1 + k0);
        if (do2) *(i32x4*)&Bsm[ld2] = *(const i32x4*)(gp2 + k0);
        *(i32x4*)&Bsm[12800 + ld0] = *(const i32x4*)(gp0 + k1);
        *(i32x4*)&Bsm[12800 + ld1] = *(const i32x4*)(gp1 + k1);
        if (do2) *(i32x4*)&Bsm[12800 + ld2] = *(const i32x4*)(gp2 + k1);
        LOAD_A(0, afX);
    }
    __syncthreads();

    for (int ph = 0; ph < 72; ++ph) {
        const int cur = ph & 1;
        const int kc0 = ph * 2, kc1 = ph * 2 + 1;
        // issue A(kc1) loads — consumed after MFMA(kc0)
        LOAD_A(kc1, afY);
        // issue B-global loads for next phase
        i32x4 sva0, sva1, sva2, svb0, svb1, svb2;
        if (ph + 1 < 72) {
            size_t ka = KOFS(kc0 + 2), kb = KOFS(kc1 + 2);
            sva0 = *(const i32x4*)(gp0 + ka);
            sva1 = *(const i32x4*)(gp1 + ka);
            if (do2) sva2 = *(const i32x4*)(gp2 + ka);
            svb0 = *(const i32x4*)(gp0 + kb);
            svb1 = *(const i32x4*)(gp1 + kb);
            if (do2) svb2 = *(const i32x4*)(gp2 + kb);
        }
        const signed char* bb0 = &Bsm[cur * 25600];
        const signed char* bb1 = &Bsm[cur * 25600 + 12800];
        // MFMA kc0 on afX (A already resident)
        MFMA_KC(bb0, afX);
        // issue A(kc0 of next phase) — hides under MFMA(kc1)
        if (ph + 1 < 72) LOAD_A(kc0 + 2, afX);
        // MFMA kc1 on afY
        MFMA_KC(bb1, afY);
        // write next phase's B to other buffer; one barrier per phase
        if (ph + 1 < 72) {
            signed char* bw = &Bsm[(cur ^ 1) * 25600];
            *(i32x4*)&bw[ld0] = sva0;
            *(i32x4*)&bw[ld1] = sva1;
            if (do2) *(i32x4*)&bw[ld2] = sva2;
            *(i32x4*)&bw[12800 + ld0] = svb0;
            *(i32x4*)&bw[12800 + ld1] = svb1;
            if (do2) *(i32x4*)&bw[12800 + ld2] = svb2;
        }
        __syncthreads();
    }
#undef KOFS
#undef LOAD_A
#undef MFMA_KC

    double sc[6];
#pragma unroll
    for (int s = 0; s < 6; ++s) sc[s] = ldexp(1.0, EA + EB - 7 * (s + 2));
#pragma unroll
    for (int rt = 0; rt < 2; ++rt)
#pragma unroll
        for (int ct = 0; ct < 2; ++ct)
#pragma unroll
            for (int r = 0; r < 4; ++r) {
                int grow = mbase + rt * 16 + dR[r];
                int gcol = n0 + ct * 16 + dC[r];
                if (grow < NPIX) {
                    double v = (double)bconv[gcol];
#pragma unroll
                    for (int s = 0; s < 6; ++s) v += sc[s] * (double)acc[s][rt][ct][r];
                    featB2[((size_t)(z * NPIX + grow)) * CMID + gcol] = fmax(v, 0.0);
                }
            }
}

// K0: W_conv -> Wt[k][co] fp32 (fallback)
__global__ void wt3x3_kernel(const float* __restrict__ W, float* __restrict__ Wt) {
    int gid = blockIdx.x * 256 + threadIdx.x;
    if (gid >= K_TOT * CMID) return;
    int co = gid & 511;
    int k  = gid >> 9;
    int pl = k >> 10;
    int ci = k & 1023;
    Wt[gid] = W[((size_t)co * CIN + ci) * 9 + pl];
}

__global__ void wt1x1_kernel(const float* __restrict__ Wc, const float* __restrict__ Wb,
                             double* __restrict__ Wt2pD) {
    int gid = blockIdx.x * 256 + threadIdx.x;
    if (gid >= CMID * 64) return;
    int n = gid & 63, k = gid >> 6;
    double v = 0.0;
    if (n < 18)      v = (double)Wc[(size_t)n * CMID + k];
    else if (n < 54) v = (double)Wb[(size_t)(n - 18) * CMID + k];
    Wt2pD[gid] = v;
}

// Fallback f64 MFMA conv (R6-verified), runs only when flags[0]==0
#define ASZ (32 * 72)
__global__ __launch_bounds__(256, 4) void conv3x3_mfma(
    const float* __restrict__ x, const float* __restrict__ Wt,
    const float* __restrict__ bconv, const int* __restrict__ tab,
    const int* __restrict__ flags, double* __restrict__ feat) {
    if (flags[0] == 1) return;
    __shared__ float As[2 * ASZ];
    __shared__ float Bs[2 * ASZ];
    const int tid = threadIdx.x;
    const int lane = tid & 63;
    const int wave = tid >> 6;
    const int wm = wave >> 1;
    const int wn = wave & 1;
    const int n0 = blockIdx.x * 64;
    const int m0 = blockIdx.y * 64;

    const int aRow = tab[lane];
    const int aK   = tab[64 + lane];
    const int bK   = tab[128 + lane];
    const int bCol = tab[192 + lane];
    int dRow[4], dCol[4];
#pragma unroll
    for (int r = 0; r < 4; ++r) {
        dRow[r] = tab[256 + lane * 4 + r];
        dCol[r] = tab[512 + lane * 4 + r];
    }
    const int mm = tid & 63;
    const int t6 = tid >> 6;
    const int m = m0 + mm;
    const bool vm = (m < M_TOT);
    int b = 0, yy = 0, xx = 0;
    if (vm) { b = m / NPIX; int r = m - b * NPIX; yy = r / FWW; xx = r - yy * FWW; }
    const int bk2 = tid >> 4;
    const int bn2 = (tid & 15) << 2;

    f64x4 acc[2][2];
#pragma unroll
    for (int i = 0; i < 2; ++i)
#pragma unroll
        for (int j = 0; j < 2; ++j) acc[i][j] = (f64x4){0.0, 0.0, 0.0, 0.0};

    const float* aBase = &As[aK * 72 + wm * 32 + aRow];
    const float* bBase = &Bs[bK * 72 + wn * 32 + bCol];

#define STAGE_REGS(KC, VA, VB0, VB1) do {                                     \
        const int pl_ = (KC) >> 5;                                            \
        const int kh_ = pl_ / 3, kw_ = pl_ - kh_ * 3;                         \
        const int ci0_ = ((KC) & 31) << 5;                                    \
        const int iy_ = yy + kh_ - 1, ix_ = xx + kw_ - 1;                     \
        const bool ok_ = vm && (iy_ >= 0) && (iy_ < FHH) && (ix_ >= 0) && (ix_ < FWW); \
        const float* ap_ = x + ((size_t)(b * CIN + ci0_ + t6)) * NPIX + iy_ * FWW + ix_; \
        _Pragma("unroll")                                                     \
        for (int r = 0; r < 8; ++r) {                                         \
            float v_ = 0.f;                                                   \
            if (ok_) v_ = ap_[(size_t)r * 4 * NPIX];                          \
            VA[r] = v_;                                                       \
        }                                                                     \
        const float4* wp_ = (const float4*)(Wt + (size_t)(((KC) << 5) + bk2) * CMID + n0 + bn2); \
        VB0 = wp_[0];                                                         \
        VB1 = wp_[2048];                                                      \
    } while (0)

#define WRITE_TILE(BUF, VA, VB0, VB1) do {                                    \
        _Pragma("unroll")                                                     \
        for (int r = 0; r < 8; ++r)                                           \
            As[(BUF) * ASZ + (t6 + r * 4) * 72 + mm] = VA[r];                 \
        *(float4*)&Bs[(BUF) * ASZ + bk2 * 72 + bn2] = VB0;                    \
        *(float4*)&Bs[(BUF) * ASZ + (bk2 + 16) * 72 + bn2] = VB1;             \
    } while (0)

#define MFMA_PHASE(BUF) do {                                                  \
        _Pragma("unroll")                                                     \
        for (int ks = 0; ks < 8; ++ks) {                                      \
            double a0 = (double)aBase[(BUF) * ASZ + ks * 288];                \
            double a1 = (double)aBase[(BUF) * ASZ + ks * 288 + 16];           \
            double b0 = (double)bBase[(BUF) * ASZ + ks * 288];                \
            double b1 = (double)bBase[(BUF) * ASZ + ks * 288 + 16];           \
            acc[0][0] = __builtin_amdgcn_mfma_f64_16x16x4f64(a0, b0, acc[0][0], 0, 0, 0); \
            acc[0][1] = __builtin_amdgcn_mfma_f64_16x16x4f64(a0, b1, acc[0][1], 0, 0, 0); \
            acc[1][0] = __builtin_amdgcn_mfma_f64_16x16x4f64(a1, b0, acc[1][0], 0, 0, 0); \
            acc[1][1] = __builtin_amdgcn_mfma_f64_16x16x4f64(a1, b1, acc[1][1], 0, 0, 0); \
        }                                                                     \
    } while (0)

    float va[8]; float4 vb0, vb1;
    float wa[8]; float4 wb0, wb1;
    STAGE_REGS(0, va, vb0, vb1);
    WRITE_TILE(0, va, vb0, vb1);
    __syncthreads();
    for (int kc = 0; kc < 288; kc += 2) {
        STAGE_REGS(kc + 1, wa, wb0, wb1);
        MFMA_PHASE(0);
        WRITE_TILE(1, wa, wb0, wb1);
        __syncthreads();
        if (kc + 2 < 288) {
            STAGE_REGS(kc + 2, va, vb0, vb1);
            MFMA_PHASE(1);
            WRITE_TILE(0, va, vb0, vb1);
            __syncthreads();
        } else {
            MFMA_PHASE(1);
        }
    }
#undef STAGE_REGS
#undef WRITE_TILE
#undef MFMA_PHASE
#pragma unroll
    for (int mi = 0; mi < 2; ++mi)
#pragma unroll
        for (int nj = 0; nj < 2; ++nj)
#pragma unroll
            for (int r = 0; r < 4; ++r) {
                int mg  = m0 + wm * 32 + mi * 16 + dRow[r];
                int col = n0 + wn * 32 + nj * 16 + dCol[r];
                if (mg < M_TOT)
                    feat[(size_t)mg * CMID + col] =
                        fmax(acc[mi][nj][r] + (double)bconv[col], 0.0);
            }
}

// K2a: 1x1 convs for ONE batch pair (i8 mode). featB2 = 4788 rows.
__global__ __launch_bounds__(256) void conv1x1_i8(
    const double* __restrict__ featB2, const double* __restrict__ Wt2pD,
    const float* __restrict__ bcls, const float* __restrict__ bbx,
    const int* __restrict__ flags, int pair, double* __restrict__ out54) {
    if (flags[0] != 1) return;
    __shared__ double As[4 * 512];
    __shared__ double Bsh[64 * 64];
    int tid = threadIdx.x;
    int m0 = blockIdx.x * 4;                   // local row in [0, 4788)
    for (int off = tid; off < 2048; off += 256) As[off] = featB2[(size_t)m0 * CMID + off];
    int p = tid >> 6, n = tid & 63;
    double acc = 0.0;
    for (int c = 0; c < 8; ++c) {
        __syncthreads();
        for (int off = tid; off < 4096; off += 256) Bsh[off] = Wt2pD[c * 4096 + off];
        __syncthreads();
        const double* ap = &As[p * 512 + c * 64];
#pragma unroll 8
        for (int k2 = 0; k2 < 64; ++k2) acc = fma(ap[k2], Bsh[k2 * 64 + n], acc);
    }
    if (n < 54) {
        double bias = (double)((n < 18) ? bcls[n] : bbx[n - 18]);
        out54[((size_t)(pair * 4788 + m0 + p)) * 64 + n] = acc + bias;
    }
}

// K2b: 1x1 convs, fallback mode (full featD)
__global__ __launch_bounds__(256) void conv1x1_fb(
    const double* __restrict__ feat, const double* __restrict__ Wt2pD,
    const float* __restrict__ bcls, const float* __restrict__ bbx,
    const int* __restrict__ flags, double* __restrict__ out54) {
    if (flags[0] == 1) return;
    __shared__ double As[4 * 512];
    __shared__ double Bsh[64 * 64];
    int tid = threadIdx.x;
    int m0 = blockIdx.x * 4;
    for (int off = tid; off < 2048; off += 256) As[off] = feat[(size_t)m0 * CMID + off];
    int p = tid >> 6, n = tid & 63;
    double acc = 0.0;
    for (int c = 0; c < 8; ++c) {
        __syncthreads();
        for (int off = tid; off < 4096; off += 256) Bsh[off] = Wt2pD[c * 4096 + off];
        __syncthreads();
        const double* ap = &As[p * 512 + c * 64];
#pragma unroll 8
        for (int k2 = 0; k2 < 64; ++k2) acc = fma(ap[k2], Bsh[k2 * 64 + n], acc);
    }
    if (n < 54) {
        double bias = (double)((n < 18) ? bcls[n] : bbx[n - 18]);
        out54[(size_t)(m0 + p) * 64 + n] = acc + bias;
    }
}

// K2c: softmax-pair + bbox decode + clip, fp64
__global__ void proposals_kernel(const double* __restrict__ out54, const float* __restrict__ iminfo,
                                 double* __restrict__ scoresD, double* __restrict__ propsD) {
    int gid = blockIdx.x * 256 + threadIdx.x;
    if (gid >= BATCH * NSC) return;
    int b = gid / NSC;
    int rem = gid - b * NSC;
    int p = rem / 9;
    int a = rem - p * 9;
    int y = p / FWW, x = p - y * FWW;
    int m = b * NPIX + p;
    const double* row = out54 + (size_t)m * 64;
    double s0 = row[a], s1 = row[9 + a];
    double mx = fmax(s0, s1);
    double e0 = exp(s0 - mx), e1 = exp(s1 - mx);
    scoresD[gid] = e1 / (e0 + e1);
    double dx = row[18 + 4 * a], dy = row[19 + 4 * a], dw = row[20 + 4 * a], dh = row[21 + 4 * a];
    double ax1 = x * 16.0 + ANCX1[a], ay1 = y * 16.0 + ANCY1[a];
    double ax2 = x * 16.0 + ANCX2[a], ay2 = y * 16.0 + ANCY2[a];
    double w = ax2 - ax1 + 1.0, h = ay2 - ay1 + 1.0;
    double cx = ax1 + 0.5 * w, cy = ay1 + 0.5 * h;
    double px = dx * w + cx, py = dy * h + cy;
    double pw = exp(dw) * w, ph = exp(dh) * h;
    double imh = (double)iminfo[b * 3 + 0], imw = (double)iminfo[b * 3 + 1];
    double x1 = fmin(fmax(px - 0.5 * pw, 0.0), imw - 1.0);
    double y1 = fmin(fmax(py - 0.5 * ph, 0.0), imh - 1.0);
    double x2 = fmin(fmax(px + 0.5 * pw, 0.0), imw - 1.0);
    double y2 = fmin(fmax(py + 0.5 * ph, 0.0), imh - 1.0);
    double* o = propsD + (size_t)gid * 4;
    o[0] = x1; o[1] = y1; o[2] = x2; o[3] = y2;
}

// K3: exact top-2000 radix-select + bitonic
__global__ __launch_bounds__(256) void select_kernel(const double* __restrict__ scoresD,
                                                     const double* __restrict__ propsD,
                                                     double* __restrict__ boxesD) {
    __shared__ unsigned int hist4[4][256];
    __shared__ unsigned int histf[256];
    __shared__ unsigned long long keys[2048];
    __shared__ unsigned long long sh_thr;
    __shared__ int sh_need;
    __shared__ int cnt;
    const int b = blockIdx.x, tid = threadIdx.x;
    const int w4 = tid >> 6;
    const double* sc = scoresD + (size_t)b * NSC;

    unsigned long long prefix = 0ull;
    int need = PRE_N;
    for (int d = 7; d >= 0; --d) {
        for (int z = tid; z < 1024; z += 256) ((unsigned int*)hist4)[z] = 0u;
        __syncthreads();
        const int shift = d * 8;
        const unsigned long long maskAbove = (d == 7) ? 0ull : (~0ull << (shift + 8));
        for (int i = tid; i < NSC; i += 256) {
            unsigned long long sb = (unsigned long long)__double_as_longlong(sc[i]);
            unsigned long long key = (sb & ~0x7FFFull) | (unsigned long long)((~i) & 0x7FFF);
            if (((key ^ prefix) & maskAbove) == 0ull)
                atomicAdd(&hist4[w4][(unsigned int)(key >> shift) & 255u], 1u);
        }
        __syncthreads();
        histf[tid] = hist4[0][tid] + hist4[1][tid] + hist4[2][tid] + hist4[3][tid];
        __syncthreads();
        if (tid == 0) {
            int acc = 0, v = 255;
            for (; v > 0; --v) {
                int c = (int)histf[v];
                if (acc + c >= need) break;
                acc += c;
            }
            sh_thr = prefix | ((unsigned long long)(unsigned int)v << shift);
            sh_need = need - acc;
        }
        __syncthreads();
        prefix = sh_thr;
        need = sh_need;
        __syncthreads();
    }
    if (tid == 0) cnt = 0;
    __syncthreads();
    for (int i = tid; i < NSC; i += 256) {
        unsigned long long sb = (unsigned long long)__double_as_longlong(sc[i]);
        unsigned long long key = (sb & ~0x7FFFull) | (unsigned long long)((~i) & 0x7FFF);
        if (key >= prefix) {
            int slot = atomicAdd(&cnt, 1);
            if (slot < 2048) keys[slot] = key;
        }
    }
    __syncthreads();
    int c0 = cnt;
    for (int i = tid; i < 2048; i += 256)
        if (i >= c0) keys[i] = 0ull;
    for (int k2 = 2; k2 <= 2048; k2 <<= 1)
        for (int j = k2 >> 1; j > 0; j >>= 1) {
            __syncthreads();
            for (int i = tid; i < 2048; i += 256) {
                int l = i ^ j;
                if (l > i) {
                    unsigned long long a = keys[i], c = keys[l];
                    bool up = (i & k2) == 0;
                    if (up ? (a < c) : (a > c)) { keys[i] = c; keys[l] = a; }
                }
            }
        }
    __syncthreads();
    const double* pr = propsD + (size_t)b * NSC * 4;
    double* bs = boxesD + (size_t)b * PRE_N * 4;
    for (int r = tid; r < PRE_N; r += 256) {
        int idx = (int)((~keys[r]) & 0x7FFF);
        if (idx >= NSC) idx = 0;
        bs[r * 4 + 0] = pr[(size_t)idx * 4 + 0];
        bs[r * 4 + 1] = pr[(size_t)idx * 4 + 1];
        bs[r * 4 + 2] = pr[(size_t)idx * 4 + 2];
        bs[r * 4 + 3] = pr[(size_t)idx * 4 + 3];
    }
}

// K4a: fp64 IoU suppression bitmask
__global__ __launch_bounds__(256) void iou_mask_kernel(const double* __restrict__ boxesD,
                                                       unsigned long long* __restrict__ supmask) {
    __shared__ double bx[PRE_N * 4];
    int b = blockIdx.x;
    int i0 = blockIdx.y * 80;
    const double* src = boxesD + (size_t)b * PRE_N * 4;
    for (int o = threadIdx.x; o < PRE_N * 4; o += 256) bx[o] = src[o];
    __syncthreads();
    int ty = threadIdx.x >> 5, jw = threadIdx.x & 31;
    for (int ii = ty; ii < 80; ii += 8) {
        int i = i0 + ii;
        double bix1 = bx[i * 4 + 0], biy1 = bx[i * 4 + 1], bix2 = bx[i * 4 + 2], biy2 = bx[i * 4 + 3];
        double areai = (bix2 - bix1 + 1.0) * (biy2 - biy1 + 1.0);
        unsigned long long bits = 0ull;
        for (int t = 0; t < 64; ++t) {
            int j = t * 32 + jw;
            if (j > i && j < PRE_N) {
                double bjx1 = bx[j * 4 + 0], bjy1 = bx[j * 4 + 1], bjx2 = bx[j * 4 + 2], bjy2 = bx[j * 4 + 3];
                double iw = fmin(bix2, bjx2) - fmax(bix1, bjx1) + 1.0; iw = fmax(iw, 0.0);
                double ih = fmin(biy2, bjy2) - fmax(biy1, bjy1) + 1.0; ih = fmax(ih, 0.0);
                double inter = iw * ih;
                double areaj = (bjx2 - bjx1 + 1.0) * (bjy2 - bjy1 + 1.0);
                double iou = inter / (areai + areaj - inter);
                if (iou > 0.7) bits |= (1ull << t);
            }
        }
        supmask[((size_t)b * PRE_N + i) * 32 + jw] = bits;
    }
}

// K4b: greedy suppression + first-300 + fp32 output
__global__ void nms_final_kernel(const unsigned long long* __restrict__ supmask,
                                 const double* __restrict__ boxesD,
                                 float* __restrict__ out) {
    int b = blockIdx.x;
    int lane = threadIdx.x;
    int w = lane & 31;
    const unsigned long long* mask = supmask + (size_t)b * PRE_N * 32;
    int nbits = (w < 16) ? 63 : 62;
    unsigned long long kw = (1ull << nbits) - 1ull;
    unsigned long long rr[16];
#pragma unroll
    for (int d2 = 0; d2 < 16; ++d2) rr[d2] = mask[d2 * 32 + w];
    for (int i = 0; i < PRE_N; i += 16) {
#pragma unroll
        for (int u2 = 0; u2 < 16; ++u2) {
            int ii = i + u2;
            unsigned long long rcur = rr[u2];
            int ip = ii + 16;
            rr[u2] = (ip < PRE_N) ? mask[ip * 32 + w] : 0ull;
            unsigned long long kword = __shfl(kw, ii & 31);
            if ((kword >> (ii >> 5)) & 1ull) kw &= ~rcur;
        }
    }
    __shared__ unsigned long long keepw[32];
    __shared__ int pos[POST_N];
    if (lane < 32) keepw[lane] = kw;
    __syncthreads();
    if (lane == 0) {
        int c2 = 0;
        for (int j = 0; j < PRE_N && c2 < POST_N; ++j)
            if ((keepw[j & 31] >> (j >> 5)) & 1ull) pos[c2++] = j;
        for (int j = 0; j < PRE_N && c2 < POST_N; ++j)
            if (!((keepw[j & 31] >> (j >> 5)) & 1ull)) pos[c2++] = j;
    }
    __syncthreads();
    for (int r = lane; r < POST_N; r += 64) {
        int p = pos[r];
        const double* bxp = boxesD + ((size_t)b * PRE_N + p) * 4;
        float* o = out + ((size_t)b * POST_N + r) * 5;
        o[0] = (float)b; o[1] = (float)bxp[0]; o[2] = (float)bxp[1];
        o[3] = (float)bxp[2]; o[4] = (float)bxp[3];
    }
    if (b == 0 && lane == 0) { out[BATCH * POST_N * 5] = 0.f; out[BATCH * POST_N * 5 + 1] = 0.f; }
}

extern "C" void kernel_launch(void* const* d_in, const int* in_sizes, int n_in,
                              void* d_out, int out_size, void* d_ws, size_t ws_size,
                              hipStream_t stream) {
    (void)in_sizes; (void)n_in; (void)out_size;
    const float* base_feat = (const float*)d_in[0];
    const float* im_info   = (const float*)d_in[1];
    const float* W_conv    = (const float*)d_in[4];
    const float* b_conv    = (const float*)d_in[5];
    const float* W_cls     = (const float*)d_in[6];
    const float* b_cls     = (const float*)d_in[7];
    const float* W_bbox    = (const float*)d_in[8];
    const float* b_bbox    = (const float*)d_in[9];
    float* out = (float*)d_out;

    // Layout (total 118,740,096 B == R9-R13-proven gate).
    char* W = (char*)d_ws;
    signed char* xsA = (signed char*)W;                   // 14,708,736
    double* featB2   = (double*)(W + 29417472);           // 19,611,648 (pair buffer)
    double* featD    = (double*)W;                        // fallback full
    float*  Wt       = (float*)(W + 78446592);            // 18,874,368 (fallback)
    signed char* ws8 = (signed char*)(W + 78446592);      // 23,592,960 (i8, clobbers Wt)
    double* out54D   = (double*)(W + 102039552);          // 9,805,824
    double* scoresD  = (double*)(W + 111845376);          // 1,378,944
    double* propsD   = (double*)(W + 113224320);          // 5,515,776 -> 118,740,096
    double* Wt2pD    = (double*)(W + 113224320);          // props-head tails (disjoint lifetime)
    int*    tab      = (int*)(W + 113486464);
    int*    itab     = (int*)(W + 113489536);
    int*    iflags   = (int*)(W + 113492608);
    unsigned long long* supmask = (unsigned long long*)W; // R0 dead after conv1x1
    double* boxesD   = scoresD;                           // written at end of select

    bool i8cap = (ws_size >= 118740096ull);

    flaginit_kernel<<<1, 64, 0, stream>>>(iflags);
    mfma_probe_kernel<<<1, 64, 0, stream>>>(tab);
    if (i8cap) {
        i8_probe_kernel<<<1, 64, 0, stream>>>(itab, iflags);
        maxabs_kernel<<<1024, 256, 0, stream>>>(base_feat, (long long)BATCH * CIN * NPIX,
                                                (unsigned*)&iflags[3]);
        maxabs_kernel<<<128, 256, 0, stream>>>(W_conv, (long long)CMID * CIN * 9,
                                               (unsigned*)&iflags[4]);
        prep_kernel<<<1, 64, 0, stream>>>(iflags);
    }
    wt3x3_kernel<<<(K_TOT * CMID + 255) / 256, 256, 0, stream>>>(W_conv, Wt);
    wt1x1_kernel<<<(CMID * 64 + 255) / 256, 256, 0, stream>>>(W_cls, W_bbox, Wt2pD);
    if (i8cap) {
        slice_w_kernel<<<(int)((4718592 + 255) / 256), 256, 0, stream>>>(W_conv, iflags, ws8);
        for (int pair = 0; pair < 4; ++pair) {
            slice_x_kernel<<<dim3(10, 64), 256, 0, stream>>>(base_feat, iflags, pair * 2, xsA);
            slice_x_kernel<<<dim3(10, 64), 256, 0, stream>>>(base_feat, iflags, pair * 2 + 1,
                                                             xsA + XS_BATCH);
            conv3x3_i8e<<<dim3(16, 19, 2), 256, 0, stream>>>(xsA, ws8, b_conv, iflags, itab,
                                                             featB2);
            conv1x1_i8<<<1197, 256, 0, stream>>>(featB2, Wt2pD, b_cls, b_bbox, iflags, pair,
                                                 out54D);
        }
    }
    conv3x3_mfma<<<dim3(8, 300), 256, 0, stream>>>(base_feat, Wt, b_conv, tab, iflags, featD);
    conv1x1_fb<<<M_TOT / 4, 256, 0, stream>>>(featD, Wt2pD, b_cls, b_bbox, iflags, out54D);
    proposals_kernel<<<(BATCH * NSC + 255) / 256, 256, 0, stream>>>(out54D, im_info, scoresD, propsD);
    select_kernel<<<BATCH, 256, 0, stream>>>(scoresD, propsD, boxesD);
    iou_mask_kernel<<<dim3(BATCH, 25), 256, 0, stream>>>(boxesD, supmask);
    nms_final_kernel<<<BATCH, 64, 0, stream>>>(supmask, boxesD, out);
}